// Round 4
// baseline (2151.406 us; speedup 1.0000x reference)
//
#include <hip/hip_runtime.h>
#include <hip/hip_bf16.h>
#include <math.h>

typedef __bf16 bf16_t;
typedef __bf16 bf16x8 __attribute__((ext_vector_type(8)));
typedef __bf16 bf16x4 __attribute__((ext_vector_type(4)));
typedef float  f32x4  __attribute__((ext_vector_type(4)));

#define GLD_LDS16(g, l)                                                          \
  __builtin_amdgcn_global_load_lds((const __attribute__((address_space(1))) void*)(g), \
                                   (__attribute__((address_space(3))) void*)(l), 16, 0, 0)

// ---------------- device-scope grid barrier (gen-flag protocol) ----------------
// Works from any initial gen value (ws poison-safe); cnt must be 0 at launch
// (memset by host each call; every barrier leaves it 0 again).
__device__ __forceinline__ void grid_barrier(int* cnt, int* gen, int nb) {
  __syncthreads();
  if (threadIdx.x == 0) {
    __threadfence();   // release: flush this XCD's writes device-wide
    int g = __hip_atomic_load(gen, __ATOMIC_ACQUIRE, __HIP_MEMORY_SCOPE_AGENT);
    int a = __hip_atomic_fetch_add(cnt, 1, __ATOMIC_ACQ_REL, __HIP_MEMORY_SCOPE_AGENT);
    if (a == nb - 1) {
      __hip_atomic_store(cnt, 0, __ATOMIC_RELAXED, __HIP_MEMORY_SCOPE_AGENT);
      __hip_atomic_fetch_add(gen, 1, __ATOMIC_ACQ_REL, __HIP_MEMORY_SCOPE_AGENT);
    } else {
      while (__hip_atomic_load(gen, __ATOMIC_ACQUIRE, __HIP_MEMORY_SCOPE_AGENT) == g)
        __builtin_amdgcn_s_sleep(8);
    }
    __threadfence();   // acquire: invalidate stale lines before next phase's reads
  }
  __syncthreads();
}

// ---------------- GEMM phase: tiles of 64x128, BK=32, 3-buf 2-deep pipeline ----------
// C[M,1024] = relu(A[M,K] @ Bw[1024,K]^T + bias). M multiple of 64, N=1024.
__device__ __forceinline__ void gemm_phase(const bf16_t* __restrict__ A,
                                           const bf16_t* __restrict__ Bw,
                                           const float* __restrict__ bias,
                                           bf16_t* __restrict__ C,
                                           int ntiles, int K, int nb,
                                           bf16_t (*As)[64 * 32], bf16_t (*Bs)[128 * 32]) {
  const int tid = threadIdx.x;
  const int lane = tid & 63;
  const int wave = tid >> 6;
  const int wr = wave >> 1, wc = wave & 1;
  const int rl = lane & 15, kq = lane >> 4;
  const int kiters = K >> 5;

  for (int wk = blockIdx.x; wk < ntiles; wk += nb) {
    const int bm = wk >> 3, bn = wk & 7;
    const bf16_t* Abase = A + (size_t)bm * 64 * K;
    const bf16_t* Bbase = Bw + (size_t)bn * 128 * K;
    f32x4 acc[2][4] = {};

    __syncthreads();   // all waves done with LDS from the previous tile

    auto stage = [&](int buf, int ko) {
      {
        int c = tid;                         // A: 64 rows x 4 chunks = 256
        int r = c >> 2, kbp = c & 3;
        int kb = kbp ^ ((r >> 1) & 3);       // inverse swizzle on global source
        GLD_LDS16(Abase + (size_t)r * K + ko + kb * 8, &As[buf][c * 8]);
      }
#pragma unroll
      for (int it = 0; it < 2; ++it) {       // B: 128 rows x 4 chunks = 512
        int c = tid + 256 * it;
        int r = c >> 2, kbp = c & 3;
        int kb = kbp ^ ((r >> 1) & 3);
        GLD_LDS16(Bbase + (size_t)r * K + ko + kb * 8, &Bs[buf][c * 8]);
      }
    };

    stage(0, 0);
    stage(1, 32);
    int cur = 0;
    for (int t = 0; t < kiters; ++t) {
      if (t + 1 < kiters) asm volatile("s_waitcnt vmcnt(3)" ::: "memory");
      else                asm volatile("s_waitcnt vmcnt(0)" ::: "memory");
      __builtin_amdgcn_s_barrier();
      __builtin_amdgcn_sched_barrier(0);
      if (t + 2 < kiters) {
        int b2 = cur + 2; if (b2 >= 3) b2 -= 3;
        stage(b2, (t + 2) * 32);
      }
      bf16x8 af[2], bfr[4];
#pragma unroll
      for (int i = 0; i < 2; ++i) {
        int r = wr * 32 + i * 16 + rl;
        int kbp = kq ^ ((r >> 1) & 3);
        af[i] = *reinterpret_cast<const bf16x8*>(&As[cur][r * 32 + kbp * 8]);
      }
#pragma unroll
      for (int j = 0; j < 4; ++j) {
        int r = wc * 64 + j * 16 + rl;
        int kbp = kq ^ ((r >> 1) & 3);
        bfr[j] = *reinterpret_cast<const bf16x8*>(&Bs[cur][r * 32 + kbp * 8]);
      }
#pragma unroll
      for (int i = 0; i < 2; ++i)
#pragma unroll
        for (int j = 0; j < 4; ++j)
          acc[i][j] = __builtin_amdgcn_mfma_f32_16x16x32_bf16(af[i], bfr[j], acc[i][j], 0, 0, 0);
      if (++cur >= 3) cur = 0;
    }

    const int rq = lane >> 4, cl = lane & 15;
#pragma unroll
    for (int j = 0; j < 4; ++j) {
      int gcol = bn * 128 + wc * 64 + j * 16 + cl;
      float bv = bias[gcol];
#pragma unroll
      for (int i = 0; i < 2; ++i) {
        int grow = bm * 64 + wr * 32 + i * 16 + rq * 4;
#pragma unroll
        for (int reg = 0; reg < 4; ++reg) {
          float v = acc[i][j][reg] + bv;
          v = v > 0.0f ? v : 0.0f;
          C[(size_t)(grow + reg) * 1024 + gcol] = (bf16_t)v;
        }
      }
    }
  }
}

// ---------------- GEMV phase: wave computes 8 rows x 1 col; loops over units --------
template <int KPL, bool RELU, bool F32OUT>
__device__ __forceinline__ void gemv_phase(const bf16_t* __restrict__ A,
                                           const bf16_t* __restrict__ Bw,
                                           const float* __restrict__ bias,
                                           void* __restrict__ Cout, int M, int nb) {
  const int K = KPL * 64;
  const int lane = threadIdx.x & 63;
  const int gw0 = blockIdx.x * 4 + (threadIdx.x >> 6);
  const int nwaves = nb * 4;
  const int units = (M >> 3) << 10;
  const int k0 = lane * KPL;
  for (int u = gw0; u < units; u += nwaves) {
    const int n = u & 1023;
    const int mb = (u >> 10) << 3;
    float bv[KPL];
    const bf16_t* bp = Bw + (size_t)n * K + k0;
#pragma unroll
    for (int q = 0; q < KPL / 8; ++q) {
      bf16x8 v = *reinterpret_cast<const bf16x8*>(bp + q * 8);
#pragma unroll
      for (int j = 0; j < 8; ++j) bv[q * 8 + j] = (float)v[j];
    }
    float acc[8];
#pragma unroll
    for (int m = 0; m < 8; ++m) {
      const bf16_t* ap = A + (size_t)(mb + m) * K + k0;
      float s = 0.0f;
#pragma unroll
      for (int q = 0; q < KPL / 8; ++q) {
        bf16x8 v = *reinterpret_cast<const bf16x8*>(ap + q * 8);
#pragma unroll
        for (int j = 0; j < 8; ++j) s += (float)v[j] * bv[q * 8 + j];
      }
      acc[m] = s;
    }
#pragma unroll
    for (int m = 0; m < 8; ++m) {
#pragma unroll
      for (int off = 32; off >= 1; off >>= 1) acc[m] += __shfl_xor(acc[m], off, 64);
    }
    if (lane < 8) {
      float v = acc[lane] + bias[n];
      if (RELU) v = v > 0.0f ? v : 0.0f;
      if (F32OUT) ((float*)Cout)[(size_t)(mb + lane) * 1024 + n] = v;
      else        ((bf16_t*)Cout)[(size_t)(mb + lane) * 1024 + n] = (bf16_t)v;
    }
  }
}

// ---------------- the whole network in one persistent kernel ----------------
__global__ __launch_bounds__(256, 4) void k_recnn(
    const float* __restrict__ leaves, const float* __restrict__ V_w,
    const float* __restrict__ V_b, const float* __restrict__ U_w,
    const float* __restrict__ U_b, const float* __restrict__ W_w,
    const float* __restrict__ W_b, const float* __restrict__ O_w,
    const float* __restrict__ O_b,
    bf16_t* leaves_bf, bf16_t* Vw_bf, bf16_t* UW_bf, bf16_t* Ow_bf,
    float* buw, bf16_t* hA, float* logits, float* out,
    int* cnt, int* gen) {
  __shared__ bf16_t As[3][64 * 32];
  __shared__ bf16_t Bs[3][128 * 32];
  __shared__ float red[8];

  const int nb = gridDim.x;
  const int tid = threadIdx.x;
  const int gtid = blockIdx.x * 256 + tid;
  const int G = nb * 256;

  // ---- phase 0: converts + UW build + summed bias ----
  for (int i = gtid; i < 2097152; i += G) {            // leaves 8M elems, x4
    float4 v = reinterpret_cast<const float4*>(leaves)[i];
    bf16x4 o; o[0] = (bf16_t)v.x; o[1] = (bf16_t)v.y; o[2] = (bf16_t)v.z; o[3] = (bf16_t)v.w;
    reinterpret_cast<bf16x4*>(leaves_bf)[i] = o;
  }
  for (int i = gtid; i < 262144; i += G) {             // V_w 1M elems, x4
    float4 v = reinterpret_cast<const float4*>(V_w)[i];
    bf16x4 o; o[0] = (bf16_t)v.x; o[1] = (bf16_t)v.y; o[2] = (bf16_t)v.z; o[3] = (bf16_t)v.w;
    reinterpret_cast<bf16x4*>(Vw_bf)[i] = o;
  }
  for (int i = gtid; i < 262144; i += G) {             // O_w 1M elems, x4
    float4 v = reinterpret_cast<const float4*>(O_w)[i];
    bf16x4 o; o[0] = (bf16_t)v.x; o[1] = (bf16_t)v.y; o[2] = (bf16_t)v.z; o[3] = (bf16_t)v.w;
    reinterpret_cast<bf16x4*>(Ow_bf)[i] = o;
  }
  for (int idx = gtid; idx < 524288; idx += G) {       // UW = [U|W], 2M elems, x4
    int i = idx * 4;
    int g = i >> 11;
    int k = i & 2047;
    const float* src = (k < 1024) ? (U_w + g * 1024 + k) : (W_w + g * 1024 + (k - 1024));
    float4 v = *reinterpret_cast<const float4*>(src);
    bf16x4 o; o[0] = (bf16_t)v.x; o[1] = (bf16_t)v.y; o[2] = (bf16_t)v.z; o[3] = (bf16_t)v.w;
    reinterpret_cast<bf16x4*>(UW_bf)[idx] = o;
  }
  if (gtid < 1024) buw[gtid] = U_b[gtid] + W_b[gtid];
  grid_barrier(cnt, gen, nb);

  // ---- phase 1: L0 GEMM 8192x1024, K=1024 (1024 tiles) ----
  gemm_phase(leaves_bf, Vw_bf, V_b, hA, 1024, 1024, nb, As, Bs);
  grid_barrier(cnt, gen, nb);

  // ---- phases 2..7: tree levels M=4096..128, K=2048 (adjacent-row trick) ----
  bf16_t* src = hA;
  bf16_t* dst = leaves_bf;      // dead after L0
  for (int M = 4096; M >= 128; M >>= 1) {
    gemm_phase(src, UW_bf, buw, dst, (M >> 6) * 8, 2048, nb, As, Bs);
    grid_barrier(cnt, gen, nb);
    bf16_t* t = src; src = dst; dst = t;
  }

  // ---- phases 8..11: tails M=64..8, K=2048 ----
  for (int M = 64; M >= 8; M >>= 1) {
    gemv_phase<32, true, false>(src, UW_bf, buw, dst, M, nb);
    grid_barrier(cnt, gen, nb);
    bf16_t* t = src; src = dst; dst = t;
  }

  // ---- phase 12: logits (8x1024, K=1024, no relu, fp32) ----
  gemv_phase<16, false, true>(src, Ow_bf, O_b, logits, 8, nb);
  grid_barrier(cnt, gen, nb);

  // ---- phase 13: log_softmax, blocks 0..7 ----
  if (blockIdx.x < 8) {
    const float* x = logits + blockIdx.x * 1024;
    int wave = tid >> 6, lane = tid & 63;
    float m = -1e30f;
    for (int i = tid; i < 1024; i += 256) m = fmaxf(m, x[i]);
#pragma unroll
    for (int off = 32; off >= 1; off >>= 1) m = fmaxf(m, __shfl_xor(m, off, 64));
    if (lane == 0) red[wave] = m;
    __syncthreads();
    m = fmaxf(fmaxf(red[0], red[1]), fmaxf(red[2], red[3]));
    float s = 0.0f;
    for (int i = tid; i < 1024; i += 256) s += expf(x[i] - m);
#pragma unroll
    for (int off = 32; off >= 1; off >>= 1) s += __shfl_xor(s, off, 64);
    if (lane == 0) red[wave] = s;
    __syncthreads();
    float lse = m + logf(red[0] + red[1] + red[2] + red[3]);
    for (int i = tid; i < 1024; i += 256) out[blockIdx.x * 1024 + i] = x[i] - lse;
  }
}

// ---------------- launch ----------------
extern "C" void kernel_launch(void* const* d_in, const int* in_sizes, int n_in,
                              void* d_out, int out_size, void* d_ws, size_t ws_size,
                              hipStream_t stream) {
  const float* leaves = (const float*)d_in[0];
  const float* V_w = (const float*)d_in[1];
  const float* V_b = (const float*)d_in[2];
  const float* U_w = (const float*)d_in[3];
  const float* U_b = (const float*)d_in[4];
  const float* W_w = (const float*)d_in[5];
  const float* W_b = (const float*)d_in[6];
  const float* O_w = (const float*)d_in[7];
  const float* O_b = (const float*)d_in[8];
  float* out = (float*)d_out;

  char* ws = (char*)d_ws;
  size_t off = 0;
  auto alloc = [&](size_t bytes) -> void* {
    off = (off + 255) & ~(size_t)255;
    void* p = ws + off;
    off += bytes;
    return p;
  };

  const size_t MB16 = (size_t)8192 * 1024 * 2;
  bf16_t* leaves_bf = (bf16_t*)alloc(MB16);
  bf16_t* Vw_bf = (bf16_t*)alloc((size_t)1024 * 1024 * 2);
  bf16_t* UW_bf = (bf16_t*)alloc((size_t)2 * 1024 * 1024 * 2);
  bf16_t* Ow_bf = (bf16_t*)alloc((size_t)1024 * 1024 * 2);
  float* buw = (float*)alloc(1024 * 4);
  bf16_t* hA = (bf16_t*)alloc(MB16);
  float* logits = (float*)alloc(8 * 1024 * 4);
  int* cnt = (int*)alloc(256);        // barrier count + generation
  int* gen = cnt + 1;
  (void)ws_size; (void)in_sizes; (void)n_in; (void)out_size;

  // count must start at 0 each call (gen may hold any value - protocol tolerates it)
  hipMemsetAsync(cnt, 0, 4, stream);

  k_recnn<<<512, 256, 0, stream>>>(leaves, V_w, V_b, U_w, U_b, W_w, W_b, O_w, O_b,
                                   leaves_bf, Vw_bf, UW_bf, Ow_bf, buw, hA, logits, out,
                                   cnt, gen);
}

// Round 5
// 849.113 us; speedup vs baseline: 2.5337x; 2.5337x over previous
//
#include <hip/hip_runtime.h>
#include <hip/hip_bf16.h>
#include <math.h>

typedef __bf16 bf16_t;
typedef __bf16 bf16x8 __attribute__((ext_vector_type(8)));
typedef __bf16 bf16x4 __attribute__((ext_vector_type(4)));
typedef float  f32x4  __attribute__((ext_vector_type(4)));

#define GLD_LDS16(g, l)                                                          \
  __builtin_amdgcn_global_load_lds((const __attribute__((address_space(1))) void*)(g), \
                                   (__attribute__((address_space(3))) void*)(l), 16, 0, 0)

// ---------------- device-scope grid barrier, minimal fencing ----------------
// Arrive: ACQ_REL fetch_add on cnt (release own writes / acquire predecessors').
// Spin:   RELAXED polls only - NO buffer_inv per iteration (the round-4 bug:
//         acquire-per-poll invalidated L2 device-wide continuously).
// Exit:   ONE acquire load of gen (single buffer_inv), sync-with last block's
//         release store of gen. No __threadfence anywhere.
// cnt must be 0 at launch (host memset); protocol tolerates any initial gen.
__device__ __forceinline__ void grid_barrier(int* cnt, int* gen, int nb) {
  __syncthreads();
  if (threadIdx.x == 0) {
    int g = __hip_atomic_load(gen, __ATOMIC_RELAXED, __HIP_MEMORY_SCOPE_AGENT);
    int a = __hip_atomic_fetch_add(cnt, 1, __ATOMIC_ACQ_REL, __HIP_MEMORY_SCOPE_AGENT);
    if (a == nb - 1) {
      __hip_atomic_store(cnt, 0, __ATOMIC_RELAXED, __HIP_MEMORY_SCOPE_AGENT);
      __hip_atomic_store(gen, g + 1, __ATOMIC_RELEASE, __HIP_MEMORY_SCOPE_AGENT);
    } else {
      int v;
      do {
        __builtin_amdgcn_s_sleep(2);
        v = __hip_atomic_load(gen, __ATOMIC_RELAXED, __HIP_MEMORY_SCOPE_AGENT);
      } while (v == g);
      v = __hip_atomic_load(gen, __ATOMIC_ACQUIRE, __HIP_MEMORY_SCOPE_AGENT);
      asm volatile("" ::"v"(v));   // keep the acquire load live
    }
  }
  __syncthreads();
}

// ---------------- GEMM phase: tiles of 64x128, BK=32, 3-buf 2-deep pipeline ----------
// C[M,1024] = relu(A[M,K] @ Bw[1024,K]^T + bias). M multiple of 64, N=1024.
__device__ __forceinline__ void gemm_phase(const bf16_t* __restrict__ A,
                                           const bf16_t* __restrict__ Bw,
                                           const float* __restrict__ bias,
                                           bf16_t* __restrict__ C,
                                           int ntiles, int K, int nb,
                                           bf16_t (*As)[64 * 32], bf16_t (*Bs)[128 * 32]) {
  const int tid = threadIdx.x;
  const int lane = tid & 63;
  const int wave = tid >> 6;
  const int wr = wave >> 1, wc = wave & 1;
  const int rl = lane & 15, kq = lane >> 4;
  const int kiters = K >> 5;

  for (int wk = blockIdx.x; wk < ntiles; wk += nb) {
    const int bm = wk >> 3, bn = wk & 7;
    const bf16_t* Abase = A + (size_t)bm * 64 * K;
    const bf16_t* Bbase = Bw + (size_t)bn * 128 * K;
    f32x4 acc[2][4] = {};

    __syncthreads();   // all waves done with LDS from the previous tile

    auto stage = [&](int buf, int ko) {
      {
        int c = tid;                         // A: 64 rows x 4 chunks = 256
        int r = c >> 2, kbp = c & 3;
        int kb = kbp ^ ((r >> 1) & 3);       // inverse swizzle on global source
        GLD_LDS16(Abase + (size_t)r * K + ko + kb * 8, &As[buf][c * 8]);
      }
#pragma unroll
      for (int it = 0; it < 2; ++it) {       // B: 128 rows x 4 chunks = 512
        int c = tid + 256 * it;
        int r = c >> 2, kbp = c & 3;
        int kb = kbp ^ ((r >> 1) & 3);
        GLD_LDS16(Bbase + (size_t)r * K + ko + kb * 8, &Bs[buf][c * 8]);
      }
    };

    stage(0, 0);
    stage(1, 32);
    int cur = 0;
    for (int t = 0; t < kiters; ++t) {
      if (t + 1 < kiters) asm volatile("s_waitcnt vmcnt(3)" ::: "memory");
      else                asm volatile("s_waitcnt vmcnt(0)" ::: "memory");
      __builtin_amdgcn_s_barrier();
      __builtin_amdgcn_sched_barrier(0);
      if (t + 2 < kiters) {
        int b2 = cur + 2; if (b2 >= 3) b2 -= 3;
        stage(b2, (t + 2) * 32);
      }
      bf16x8 af[2], bfr[4];
#pragma unroll
      for (int i = 0; i < 2; ++i) {
        int r = wr * 32 + i * 16 + rl;
        int kbp = kq ^ ((r >> 1) & 3);
        af[i] = *reinterpret_cast<const bf16x8*>(&As[cur][r * 32 + kbp * 8]);
      }
#pragma unroll
      for (int j = 0; j < 4; ++j) {
        int r = wc * 64 + j * 16 + rl;
        int kbp = kq ^ ((r >> 1) & 3);
        bfr[j] = *reinterpret_cast<const bf16x8*>(&Bs[cur][r * 32 + kbp * 8]);
      }
#pragma unroll
      for (int i = 0; i < 2; ++i)
#pragma unroll
        for (int j = 0; j < 4; ++j)
          acc[i][j] = __builtin_amdgcn_mfma_f32_16x16x32_bf16(af[i], bfr[j], acc[i][j], 0, 0, 0);
      if (++cur >= 3) cur = 0;
    }

    const int rq = lane >> 4, cl = lane & 15;
#pragma unroll
    for (int j = 0; j < 4; ++j) {
      int gcol = bn * 128 + wc * 64 + j * 16 + cl;
      float bv = bias[gcol];
#pragma unroll
      for (int i = 0; i < 2; ++i) {
        int grow = bm * 64 + wr * 32 + i * 16 + rq * 4;
#pragma unroll
        for (int reg = 0; reg < 4; ++reg) {
          float v = acc[i][j][reg] + bv;
          v = v > 0.0f ? v : 0.0f;
          C[(size_t)(grow + reg) * 1024 + gcol] = (bf16_t)v;
        }
      }
    }
  }
}

// ---------------- GEMV phase: wave computes 8 rows x 1 col; loops over units --------
template <int KPL, bool RELU, bool F32OUT>
__device__ __forceinline__ void gemv_phase(const bf16_t* __restrict__ A,
                                           const bf16_t* __restrict__ Bw,
                                           const float* __restrict__ bias,
                                           void* __restrict__ Cout, int M, int nb) {
  const int K = KPL * 64;
  const int lane = threadIdx.x & 63;
  const int gw0 = blockIdx.x * 4 + (threadIdx.x >> 6);
  const int nwaves = nb * 4;
  const int units = (M >> 3) << 10;
  const int k0 = lane * KPL;
  for (int u = gw0; u < units; u += nwaves) {
    const int n = u & 1023;
    const int mb = (u >> 10) << 3;
    float bv[KPL];
    const bf16_t* bp = Bw + (size_t)n * K + k0;
#pragma unroll
    for (int q = 0; q < KPL / 8; ++q) {
      bf16x8 v = *reinterpret_cast<const bf16x8*>(bp + q * 8);
#pragma unroll
      for (int j = 0; j < 8; ++j) bv[q * 8 + j] = (float)v[j];
    }
    float acc[8];
#pragma unroll
    for (int m = 0; m < 8; ++m) {
      const bf16_t* ap = A + (size_t)(mb + m) * K + k0;
      float s = 0.0f;
#pragma unroll
      for (int q = 0; q < KPL / 8; ++q) {
        bf16x8 v = *reinterpret_cast<const bf16x8*>(ap + q * 8);
#pragma unroll
        for (int j = 0; j < 8; ++j) s += (float)v[j] * bv[q * 8 + j];
      }
      acc[m] = s;
    }
#pragma unroll
    for (int m = 0; m < 8; ++m) {
#pragma unroll
      for (int off = 32; off >= 1; off >>= 1) acc[m] += __shfl_xor(acc[m], off, 64);
    }
    if (lane < 8) {
      float v = acc[lane] + bias[n];
      if (RELU) v = v > 0.0f ? v : 0.0f;
      if (F32OUT) ((float*)Cout)[(size_t)(mb + lane) * 1024 + n] = v;
      else        ((bf16_t*)Cout)[(size_t)(mb + lane) * 1024 + n] = (bf16_t)v;
    }
  }
}

// ---------------- the whole network in one persistent kernel ----------------
__global__ __launch_bounds__(256, 4) void k_recnn(
    const float* __restrict__ leaves, const float* __restrict__ V_w,
    const float* __restrict__ V_b, const float* __restrict__ U_w,
    const float* __restrict__ U_b, const float* __restrict__ W_w,
    const float* __restrict__ W_b, const float* __restrict__ O_w,
    const float* __restrict__ O_b,
    bf16_t* leaves_bf, bf16_t* Vw_bf, bf16_t* UW_bf, bf16_t* Ow_bf,
    float* buw, bf16_t* hA, float* logits, float* out,
    int* cnt, int* gen) {
  __shared__ bf16_t As[3][64 * 32];
  __shared__ bf16_t Bs[3][128 * 32];
  __shared__ float red[8];

  const int nb = gridDim.x;
  const int tid = threadIdx.x;
  const int gtid = blockIdx.x * 256 + tid;
  const int G = nb * 256;

  // ---- phase 0: converts + UW build + summed bias ----
  for (int i = gtid; i < 2097152; i += G) {            // leaves 8M elems, x4
    float4 v = reinterpret_cast<const float4*>(leaves)[i];
    bf16x4 o; o[0] = (bf16_t)v.x; o[1] = (bf16_t)v.y; o[2] = (bf16_t)v.z; o[3] = (bf16_t)v.w;
    reinterpret_cast<bf16x4*>(leaves_bf)[i] = o;
  }
  for (int i = gtid; i < 262144; i += G) {             // V_w 1M elems, x4
    float4 v = reinterpret_cast<const float4*>(V_w)[i];
    bf16x4 o; o[0] = (bf16_t)v.x; o[1] = (bf16_t)v.y; o[2] = (bf16_t)v.z; o[3] = (bf16_t)v.w;
    reinterpret_cast<bf16x4*>(Vw_bf)[i] = o;
  }
  for (int i = gtid; i < 262144; i += G) {             // O_w 1M elems, x4
    float4 v = reinterpret_cast<const float4*>(O_w)[i];
    bf16x4 o; o[0] = (bf16_t)v.x; o[1] = (bf16_t)v.y; o[2] = (bf16_t)v.z; o[3] = (bf16_t)v.w;
    reinterpret_cast<bf16x4*>(Ow_bf)[i] = o;
  }
  for (int idx = gtid; idx < 524288; idx += G) {       // UW = [U|W], 2M elems, x4
    int i = idx * 4;
    int g = i >> 11;
    int k = i & 2047;
    const float* src = (k < 1024) ? (U_w + g * 1024 + k) : (W_w + g * 1024 + (k - 1024));
    float4 v = *reinterpret_cast<const float4*>(src);
    bf16x4 o; o[0] = (bf16_t)v.x; o[1] = (bf16_t)v.y; o[2] = (bf16_t)v.z; o[3] = (bf16_t)v.w;
    reinterpret_cast<bf16x4*>(UW_bf)[idx] = o;
  }
  if (gtid < 1024) buw[gtid] = U_b[gtid] + W_b[gtid];
  grid_barrier(cnt, gen, nb);

  // ---- phase 1: L0 GEMM 8192x1024, K=1024 (1024 tiles) ----
  gemm_phase(leaves_bf, Vw_bf, V_b, hA, 1024, 1024, nb, As, Bs);
  grid_barrier(cnt, gen, nb);

  // ---- phases 2..7: tree levels M=4096..128, K=2048 (adjacent-row trick) ----
  bf16_t* src = hA;
  bf16_t* dst = leaves_bf;      // dead after L0
  for (int M = 4096; M >= 128; M >>= 1) {
    gemm_phase(src, UW_bf, buw, dst, (M >> 6) * 8, 2048, nb, As, Bs);
    grid_barrier(cnt, gen, nb);
    bf16_t* t = src; src = dst; dst = t;
  }

  // ---- phases 8..11: tails M=64..8, K=2048 ----
  for (int M = 64; M >= 8; M >>= 1) {
    gemv_phase<32, true, false>(src, UW_bf, buw, dst, M, nb);
    grid_barrier(cnt, gen, nb);
    bf16_t* t = src; src = dst; dst = t;
  }

  // ---- phase 12: logits (8x1024, K=1024, no relu, fp32) ----
  gemv_phase<16, false, true>(src, Ow_bf, O_b, logits, 8, nb);
  grid_barrier(cnt, gen, nb);

  // ---- phase 13: log_softmax, blocks 0..7 ----
  if (blockIdx.x < 8) {
    const float* x = logits + blockIdx.x * 1024;
    int wave = tid >> 6, lane = tid & 63;
    float m = -1e30f;
    for (int i = tid; i < 1024; i += 256) m = fmaxf(m, x[i]);
#pragma unroll
    for (int off = 32; off >= 1; off >>= 1) m = fmaxf(m, __shfl_xor(m, off, 64));
    if (lane == 0) red[wave] = m;
    __syncthreads();
    m = fmaxf(fmaxf(red[0], red[1]), fmaxf(red[2], red[3]));
    float s = 0.0f;
    for (int i = tid; i < 1024; i += 256) s += expf(x[i] - m);
#pragma unroll
    for (int off = 32; off >= 1; off >>= 1) s += __shfl_xor(s, off, 64);
    if (lane == 0) red[wave] = s;
    __syncthreads();
    float lse = m + logf(red[0] + red[1] + red[2] + red[3]);
    for (int i = tid; i < 1024; i += 256) out[blockIdx.x * 1024 + i] = x[i] - lse;
  }
}

// ---------------- launch ----------------
extern "C" void kernel_launch(void* const* d_in, const int* in_sizes, int n_in,
                              void* d_out, int out_size, void* d_ws, size_t ws_size,
                              hipStream_t stream) {
  const float* leaves = (const float*)d_in[0];
  const float* V_w = (const float*)d_in[1];
  const float* V_b = (const float*)d_in[2];
  const float* U_w = (const float*)d_in[3];
  const float* U_b = (const float*)d_in[4];
  const float* W_w = (const float*)d_in[5];
  const float* W_b = (const float*)d_in[6];
  const float* O_w = (const float*)d_in[7];
  const float* O_b = (const float*)d_in[8];
  float* out = (float*)d_out;

  char* ws = (char*)d_ws;
  size_t off = 0;
  auto alloc = [&](size_t bytes) -> void* {
    off = (off + 255) & ~(size_t)255;
    void* p = ws + off;
    off += bytes;
    return p;
  };

  const size_t MB16 = (size_t)8192 * 1024 * 2;
  bf16_t* leaves_bf = (bf16_t*)alloc(MB16);
  bf16_t* Vw_bf = (bf16_t*)alloc((size_t)1024 * 1024 * 2);
  bf16_t* UW_bf = (bf16_t*)alloc((size_t)2 * 1024 * 1024 * 2);
  bf16_t* Ow_bf = (bf16_t*)alloc((size_t)1024 * 1024 * 2);
  float* buw = (float*)alloc(1024 * 4);
  bf16_t* hA = (bf16_t*)alloc(MB16);
  float* logits = (float*)alloc(8 * 1024 * 4);
  int* cnt = (int*)alloc(256);        // barrier count + generation
  int* gen = cnt + 1;
  (void)ws_size; (void)in_sizes; (void)n_in; (void)out_size;

  // count must start at 0 each call (gen may hold any value - protocol tolerates it)
  hipMemsetAsync(cnt, 0, 4, stream);

  k_recnn<<<512, 256, 0, stream>>>(leaves, V_w, V_b, U_w, U_b, W_w, W_b, O_w, O_b,
                                   leaves_bf, Vw_bf, UW_bf, Ow_bf, buw, hA, logits, out,
                                   cnt, gen);
}

// Round 6
// 274.273 us; speedup vs baseline: 7.8440x; 3.0959x over previous
//
#include <hip/hip_runtime.h>
#include <hip/hip_bf16.h>
#include <math.h>

typedef __bf16 bf16_t;
typedef __bf16 bf16x8 __attribute__((ext_vector_type(8)));
typedef __bf16 bf16x4 __attribute__((ext_vector_type(4)));
typedef float  f32x4  __attribute__((ext_vector_type(4)));

#define GLD_LDS16(g, l)                                                          \
  __builtin_amdgcn_global_load_lds((const __attribute__((address_space(1))) void*)(g), \
                                   (__attribute__((address_space(3))) void*)(l), 16, 0, 0)

// ---------------- fused converts: leaves/V_w/O_w -> bf16, UW=[U|W], buw=Ub+Wb -------
__global__ __launch_bounds__(256) void k_cvt_all(const float* __restrict__ leaves,
                                                 const float* __restrict__ V_w,
                                                 const float* __restrict__ O_w,
                                                 const float* __restrict__ U_w,
                                                 const float* __restrict__ W_w,
                                                 const float* __restrict__ U_b,
                                                 const float* __restrict__ W_b,
                                                 bf16_t* __restrict__ leaves_bf,
                                                 bf16_t* __restrict__ Vw_bf,
                                                 bf16_t* __restrict__ Ow_bf,
                                                 bf16_t* __restrict__ UW_bf,
                                                 float* __restrict__ buw) {
  const int gtid = blockIdx.x * 256 + threadIdx.x;
  const int G = gridDim.x * 256;
  for (int i = gtid; i < 2097152; i += G) {            // leaves: 8M elems / 4
    float4 v = reinterpret_cast<const float4*>(leaves)[i];
    bf16x4 o; o[0] = (bf16_t)v.x; o[1] = (bf16_t)v.y; o[2] = (bf16_t)v.z; o[3] = (bf16_t)v.w;
    reinterpret_cast<bf16x4*>(leaves_bf)[i] = o;
  }
  for (int i = gtid; i < 262144; i += G) {             // V_w
    float4 v = reinterpret_cast<const float4*>(V_w)[i];
    bf16x4 o; o[0] = (bf16_t)v.x; o[1] = (bf16_t)v.y; o[2] = (bf16_t)v.z; o[3] = (bf16_t)v.w;
    reinterpret_cast<bf16x4*>(Vw_bf)[i] = o;
  }
  for (int i = gtid; i < 262144; i += G) {             // O_w
    float4 v = reinterpret_cast<const float4*>(O_w)[i];
    bf16x4 o; o[0] = (bf16_t)v.x; o[1] = (bf16_t)v.y; o[2] = (bf16_t)v.z; o[3] = (bf16_t)v.w;
    reinterpret_cast<bf16x4*>(Ow_bf)[i] = o;
  }
  for (int idx = gtid; idx < 524288; idx += G) {       // UW = [U|W] concat along K
    int i = idx * 4;
    int g = i >> 11;
    int k = i & 2047;
    const float* src = (k < 1024) ? (U_w + g * 1024 + k) : (W_w + g * 1024 + (k - 1024));
    float4 v = *reinterpret_cast<const float4*>(src);
    bf16x4 o; o[0] = (bf16_t)v.x; o[1] = (bf16_t)v.y; o[2] = (bf16_t)v.z; o[3] = (bf16_t)v.w;
    reinterpret_cast<bf16x4*>(UW_bf)[idx] = o;
  }
  if (gtid < 1024) buw[gtid] = U_b[gtid] + W_b[gtid];
}

// ---------------- GEMM: TMxTN tile, BK=32, 3-buf 2-deep pipeline, counted vmcnt -----
// C[M,1024] = relu(A[M,K] @ Bw[1024,K]^T + bias). M,TM multiples of 64.
// Waves 2x2: wave tile (TM/2)x(TN/2). Per-thread gld/stage = TM/64 + TN/64.
template <int TM, int TN>
__global__ __launch_bounds__(256, 4) void k_gemm(const bf16_t* __restrict__ A,
                                                 const bf16_t* __restrict__ Bw,
                                                 const float* __restrict__ bias,
                                                 bf16_t* __restrict__ C,
                                                 int K) {
  constexpr int MI = TM / 32;                 // row frags per wave
  constexpr int NJ = TN / 32;                 // col frags per wave
  constexpr int VM = TM / 64 + TN / 64;       // per-thread loads per stage
  __shared__ bf16_t As[3][TM * 32];
  __shared__ bf16_t Bs[3][TN * 32];

  const int tid = threadIdx.x;
  const int lane = tid & 63;
  const int wave = tid >> 6;
  const int wr = wave >> 1, wc = wave & 1;
  const int bm = blockIdx.x, bn = blockIdx.y;

  const bf16_t* Abase = A + (size_t)bm * TM * K;
  const bf16_t* Bbase = Bw + (size_t)bn * TN * K;

  f32x4 acc[MI][NJ] = {};
  const int rl = lane & 15, kq = lane >> 4;

  auto stage = [&](int buf, int ko) {
#pragma unroll
    for (int it = 0; it < TM / 64; ++it) {    // A: TM rows x 4 chunks
      int c = tid + 256 * it;
      int r = c >> 2, kbp = c & 3;
      int kb = kbp ^ ((r >> 1) & 3);          // inverse swizzle on global source
      GLD_LDS16(Abase + (size_t)r * K + ko + kb * 8, &As[buf][c * 8]);
    }
#pragma unroll
    for (int it = 0; it < TN / 64; ++it) {    // B: TN rows x 4 chunks
      int c = tid + 256 * it;
      int r = c >> 2, kbp = c & 3;
      int kb = kbp ^ ((r >> 1) & 3);
      GLD_LDS16(Bbase + (size_t)r * K + ko + kb * 8, &Bs[buf][c * 8]);
    }
  };

  const int kiters = K >> 5;
  stage(0, 0);
  stage(1, 32);

  int cur = 0;
  for (int t = 0; t < kiters; ++t) {
    if (t + 1 < kiters) asm volatile("s_waitcnt vmcnt(%0)" :: "i"(VM) : "memory");
    else                asm volatile("s_waitcnt vmcnt(0)" ::: "memory");
    __builtin_amdgcn_s_barrier();
    __builtin_amdgcn_sched_barrier(0);
    if (t + 2 < kiters) {
      int b2 = cur + 2; if (b2 >= 3) b2 -= 3;
      stage(b2, (t + 2) * 32);
    }
    bf16x8 af[MI], bfr[NJ];
#pragma unroll
    for (int i = 0; i < MI; ++i) {
      int r = wr * (TM / 2) + i * 16 + rl;
      int kbp = kq ^ ((r >> 1) & 3);
      af[i] = *reinterpret_cast<const bf16x8*>(&As[cur][r * 32 + kbp * 8]);
    }
#pragma unroll
    for (int j = 0; j < NJ; ++j) {
      int r = wc * (TN / 2) + j * 16 + rl;
      int kbp = kq ^ ((r >> 1) & 3);
      bfr[j] = *reinterpret_cast<const bf16x8*>(&Bs[cur][r * 32 + kbp * 8]);
    }
#pragma unroll
    for (int i = 0; i < MI; ++i)
#pragma unroll
      for (int j = 0; j < NJ; ++j)
        acc[i][j] = __builtin_amdgcn_mfma_f32_16x16x32_bf16(af[i], bfr[j], acc[i][j], 0, 0, 0);
    if (++cur >= 3) cur = 0;
  }

  const int rq = lane >> 4, cl = lane & 15;
#pragma unroll
  for (int j = 0; j < NJ; ++j) {
    int gcol = bn * TN + wc * (TN / 2) + j * 16 + cl;
    float bv = bias[gcol];
#pragma unroll
    for (int i = 0; i < MI; ++i) {
      int grow = bm * TM + wr * (TM / 2) + i * 16 + rq * 4;
#pragma unroll
      for (int reg = 0; reg < 4; ++reg) {
        float v = acc[i][j][reg] + bv;
        v = v > 0.0f ? v : 0.0f;
        C[(size_t)(grow + reg) * 1024 + gcol] = (bf16_t)v;
      }
    }
  }
}

// ---------------- tiny levels (M<=64): wave-per-column GEMV, 8 rows per wave --------
__global__ __launch_bounds__(256) void k_tail(const bf16_t* __restrict__ A,
                                              const bf16_t* __restrict__ Bw,
                                              const float* __restrict__ bias,
                                              bf16_t* __restrict__ C, int M) {
  constexpr int N = 1024, K = 2048;
  const int lane = threadIdx.x & 63;
  const int gw = blockIdx.x * 4 + (threadIdx.x >> 6);
  const int n = gw & (N - 1);
  const int mbase = (gw >> 10) * 8;
  const int k0 = lane * 32;

  float bv[32];
  const bf16_t* bp = Bw + (size_t)n * K + k0;
#pragma unroll
  for (int q = 0; q < 4; ++q) {
    bf16x8 v = *reinterpret_cast<const bf16x8*>(bp + q * 8);
#pragma unroll
    for (int j = 0; j < 8; ++j) bv[q * 8 + j] = (float)v[j];
  }

  float acc[8];
#pragma unroll
  for (int m = 0; m < 8; ++m) {
    const bf16_t* ap = A + (size_t)(mbase + m) * K + k0;
    float s = 0.0f;
#pragma unroll
    for (int q = 0; q < 4; ++q) {
      bf16x8 v = *reinterpret_cast<const bf16x8*>(ap + q * 8);
#pragma unroll
      for (int j = 0; j < 8; ++j) s += (float)v[j] * bv[q * 8 + j];
    }
    acc[m] = s;
  }
#pragma unroll
  for (int m = 0; m < 8; ++m) {
#pragma unroll
    for (int off = 32; off >= 1; off >>= 1) acc[m] += __shfl_xor(acc[m], off, 64);
  }
  if (lane < 8 && mbase + lane < M) {
    float v = acc[lane] + bias[n];
    v = v > 0.0f ? v : 0.0f;
    C[(size_t)(mbase + lane) * N + n] = (bf16_t)v;
  }
}

// ---------------- logits ----------------
__global__ __launch_bounds__(256) void k_logits(const bf16_t* __restrict__ root,
                                                const bf16_t* __restrict__ Ow,
                                                const float* __restrict__ Ob,
                                                float* __restrict__ out) {
  int o = blockIdx.x * 256 + threadIdx.x;
  int b = blockIdx.y;
  const bf16_t* r = root + b * 1024;
  const bf16_t* w = Ow + (size_t)o * 1024;
  float s = 0.0f;
#pragma unroll 4
  for (int k = 0; k < 1024; k += 8) {
    bf16x8 rv = *reinterpret_cast<const bf16x8*>(r + k);
    bf16x8 wv = *reinterpret_cast<const bf16x8*>(w + k);
#pragma unroll
    for (int j = 0; j < 8; ++j) s += (float)rv[j] * (float)wv[j];
  }
  out[b * 1024 + o] = s + Ob[o];
}

// ---------------- log_softmax ----------------
__global__ __launch_bounds__(256) void k_logsoftmax(const float* __restrict__ logits,
                                                    float* __restrict__ out) {
  int b = blockIdx.x;
  const float* x = logits + b * 1024;
  int tid = threadIdx.x;
  int wave = tid >> 6, lane = tid & 63;
  __shared__ float red[8];

  float m = -1e30f;
  for (int i = tid; i < 1024; i += 256) m = fmaxf(m, x[i]);
#pragma unroll
  for (int off = 32; off >= 1; off >>= 1) m = fmaxf(m, __shfl_xor(m, off, 64));
  if (lane == 0) red[wave] = m;
  __syncthreads();
  m = fmaxf(fmaxf(red[0], red[1]), fmaxf(red[2], red[3]));
  float s = 0.0f;
  for (int i = tid; i < 1024; i += 256) s += expf(x[i] - m);
#pragma unroll
  for (int off = 32; off >= 1; off >>= 1) s += __shfl_xor(s, off, 64);
  if (lane == 0) red[wave] = s;
  __syncthreads();
  float lse = m + logf(red[0] + red[1] + red[2] + red[3]);
  for (int i = tid; i < 1024; i += 256) out[b * 1024 + i] = x[i] - lse;
}

// ---------------- launch ----------------
extern "C" void kernel_launch(void* const* d_in, const int* in_sizes, int n_in,
                              void* d_out, int out_size, void* d_ws, size_t ws_size,
                              hipStream_t stream) {
  const float* leaves = (const float*)d_in[0];
  const float* V_w = (const float*)d_in[1];
  const float* V_b = (const float*)d_in[2];
  const float* U_w = (const float*)d_in[3];
  const float* U_b = (const float*)d_in[4];
  const float* W_w = (const float*)d_in[5];
  const float* W_b = (const float*)d_in[6];
  const float* O_w = (const float*)d_in[7];
  const float* O_b = (const float*)d_in[8];
  float* out = (float*)d_out;

  char* ws = (char*)d_ws;
  size_t off = 0;
  auto alloc = [&](size_t bytes) -> void* {
    off = (off + 255) & ~(size_t)255;
    void* p = ws + off;
    off += bytes;
    return p;
  };

  const size_t MB16 = (size_t)8192 * 1024 * 2;
  bf16_t* leaves_bf = (bf16_t*)alloc(MB16);
  bf16_t* Vw_bf = (bf16_t*)alloc((size_t)1024 * 1024 * 2);
  bf16_t* UW_bf = (bf16_t*)alloc((size_t)2 * 1024 * 1024 * 2);
  bf16_t* Ow_bf = (bf16_t*)alloc((size_t)1024 * 1024 * 2);
  float* buw = (float*)alloc(1024 * 4);
  bf16_t* hA = (bf16_t*)alloc(MB16);
  float* logits = (float*)alloc(8 * 1024 * 4);
  (void)ws_size; (void)in_sizes; (void)n_in; (void)out_size;

  // 1: fused converts
  k_cvt_all<<<2048, 256, 0, stream>>>(leaves, V_w, O_w, U_w, W_w, U_b, W_b,
                                      leaves_bf, Vw_bf, Ow_bf, UW_bf, buw);

  // 2: L0 GEMM 8192x1024, K=1024 -> grid(128,8) = 1024 blocks
  k_gemm<64, 128><<<dim3(128, 8), 256, 0, stream>>>(leaves_bf, Vw_bf, V_b, hA, 1024);

  bf16_t* src = hA;
  bf16_t* dst = leaves_bf;
  auto swap = [&]() { bf16_t* t = src; src = dst; dst = t; };

  // 3: M=4096, K=2048 -> grid(64,8) = 512 blocks
  k_gemm<64, 128><<<dim3(64, 8), 256, 0, stream>>>(src, UW_bf, buw, dst, 2048);
  swap();
  // 4-8: M=2048..128, K=2048, N-split TN=64 -> grid(M/64, 16)
  for (int M = 2048; M >= 128; M >>= 1) {
    k_gemm<64, 64><<<dim3(M / 64, 16), 256, 0, stream>>>(src, UW_bf, buw, dst, 2048);
    swap();
  }
  // 9-12: tails M=64..8 (wave-per-column GEMV)
  for (int M = 64; M >= 8; M >>= 1) {
    int blocks = (M / 8) * 1024 / 4;
    k_tail<<<blocks, 256, 0, stream>>>(src, UW_bf, buw, dst, M);
    swap();
  }

  // 13-14: logits + log_softmax
  k_logits<<<dim3(4, 8), 256, 0, stream>>>(src, Ow_bf, O_b, logits);
  k_logsoftmax<<<8, 256, 0, stream>>>(logits, out);
}

// Round 7
// 269.951 us; speedup vs baseline: 7.9696x; 1.0160x over previous
//
#include <hip/hip_runtime.h>
#include <hip/hip_bf16.h>
#include <math.h>

typedef __bf16 bf16_t;
typedef __bf16 bf16x8 __attribute__((ext_vector_type(8)));
typedef __bf16 bf16x4 __attribute__((ext_vector_type(4)));
typedef float  f32x4  __attribute__((ext_vector_type(4)));

#define GLD_LDS16(g, l)                                                          \
  __builtin_amdgcn_global_load_lds((const __attribute__((address_space(1))) void*)(g), \
                                   (__attribute__((address_space(3))) void*)(l), 16, 0, 0)

// ---------------- fused converts: leaves/V_w/O_w -> bf16, UW=[U|W], buw=Ub+Wb -------
__global__ __launch_bounds__(256) void k_cvt_all(const float* __restrict__ leaves,
                                                 const float* __restrict__ V_w,
                                                 const float* __restrict__ O_w,
                                                 const float* __restrict__ U_w,
                                                 const float* __restrict__ W_w,
                                                 const float* __restrict__ U_b,
                                                 const float* __restrict__ W_b,
                                                 bf16_t* __restrict__ leaves_bf,
                                                 bf16_t* __restrict__ Vw_bf,
                                                 bf16_t* __restrict__ Ow_bf,
                                                 bf16_t* __restrict__ UW_bf,
                                                 float* __restrict__ buw) {
  const int gtid = blockIdx.x * 256 + threadIdx.x;
  const int G = gridDim.x * 256;
  for (int i = gtid; i < 2097152; i += G) {            // leaves: 8M elems / 4
    float4 v = reinterpret_cast<const float4*>(leaves)[i];
    bf16x4 o; o[0] = (bf16_t)v.x; o[1] = (bf16_t)v.y; o[2] = (bf16_t)v.z; o[3] = (bf16_t)v.w;
    reinterpret_cast<bf16x4*>(leaves_bf)[i] = o;
  }
  for (int i = gtid; i < 262144; i += G) {             // V_w
    float4 v = reinterpret_cast<const float4*>(V_w)[i];
    bf16x4 o; o[0] = (bf16_t)v.x; o[1] = (bf16_t)v.y; o[2] = (bf16_t)v.z; o[3] = (bf16_t)v.w;
    reinterpret_cast<bf16x4*>(Vw_bf)[i] = o;
  }
  for (int i = gtid; i < 262144; i += G) {             // O_w
    float4 v = reinterpret_cast<const float4*>(O_w)[i];
    bf16x4 o; o[0] = (bf16_t)v.x; o[1] = (bf16_t)v.y; o[2] = (bf16_t)v.z; o[3] = (bf16_t)v.w;
    reinterpret_cast<bf16x4*>(Ow_bf)[i] = o;
  }
  for (int idx = gtid; idx < 524288; idx += G) {       // UW = [U|W] concat along K
    int i = idx * 4;
    int g = i >> 11;
    int k = i & 2047;
    const float* src = (k < 1024) ? (U_w + g * 1024 + k) : (W_w + g * 1024 + (k - 1024));
    float4 v = *reinterpret_cast<const float4*>(src);
    bf16x4 o; o[0] = (bf16_t)v.x; o[1] = (bf16_t)v.y; o[2] = (bf16_t)v.z; o[3] = (bf16_t)v.w;
    reinterpret_cast<bf16x4*>(UW_bf)[idx] = o;
  }
  if (gtid < 1024) buw[gtid] = U_b[gtid] + W_b[gtid];
}

// ---------------- GEMM: TMxTN tile, BK=32, 3-buf 2-deep pipeline, counted vmcnt -----
// C[M,1024] = relu(A[M,Kstride(chunk)] @ Bw[1024,Kstride]^T + bias), or fp32 partials.
// Waves 2x2: wave tile (TM/2)x(TN/2), MI*NJ MFMA per K-step.
template <int TM, int TN, bool SPLIT>
__global__ __launch_bounds__(256, (TM == 128 ? 3 : 4)) void k_gemm(
    const bf16_t* __restrict__ A, const bf16_t* __restrict__ Bw,
    const float* __restrict__ bias, bf16_t* __restrict__ C,
    float* __restrict__ P, int M, int Kstride, int kchunk) {
  constexpr int MI = TM / 32;                 // row frags per wave
  constexpr int NJ = TN / 32;                 // col frags per wave
  constexpr int VM = TM / 64 + TN / 64;       // per-thread loads per stage
  __shared__ bf16_t As[3][TM * 32];
  __shared__ bf16_t Bs[3][TN * 32];

  const int tid = threadIdx.x;
  const int lane = tid & 63;
  const int wave = tid >> 6;
  const int wr = wave >> 1, wc = wave & 1;
  const int bm = blockIdx.x, bn = blockIdx.y, bz = blockIdx.z;

  const bf16_t* Abase = A + (size_t)bm * TM * Kstride + (size_t)bz * kchunk;
  const bf16_t* Bbase = Bw + (size_t)bn * TN * Kstride + (size_t)bz * kchunk;

  f32x4 acc[MI][NJ] = {};
  const int rl = lane & 15, kq = lane >> 4;

  auto stage = [&](int buf, int ko) {
#pragma unroll
    for (int it = 0; it < TM / 64; ++it) {    // A: TM rows x 4 chunks of 8 bf16
      int c = tid + 256 * it;
      int r = c >> 2, kbp = c & 3;
      int kb = kbp ^ ((r >> 1) & 3);          // inverse swizzle on global source
      GLD_LDS16(Abase + (size_t)r * Kstride + ko + kb * 8, &As[buf][c * 8]);
    }
#pragma unroll
    for (int it = 0; it < TN / 64; ++it) {    // B: TN rows x 4 chunks
      int c = tid + 256 * it;
      int r = c >> 2, kbp = c & 3;
      int kb = kbp ^ ((r >> 1) & 3);
      GLD_LDS16(Bbase + (size_t)r * Kstride + ko + kb * 8, &Bs[buf][c * 8]);
    }
  };

  const int kiters = kchunk >> 5;
  stage(0, 0);
  stage(1, 32);

  int cur = 0;
  for (int t = 0; t < kiters; ++t) {
    if (t + 1 < kiters) asm volatile("s_waitcnt vmcnt(%0)" :: "i"(VM) : "memory");
    else                asm volatile("s_waitcnt vmcnt(0)" ::: "memory");
    __builtin_amdgcn_s_barrier();
    __builtin_amdgcn_sched_barrier(0);
    if (t + 2 < kiters) {
      int b2 = cur + 2; if (b2 >= 3) b2 -= 3;
      stage(b2, (t + 2) * 32);
    }
    bf16x8 af[MI], bfr[NJ];
#pragma unroll
    for (int i = 0; i < MI; ++i) {
      int r = wr * (TM / 2) + i * 16 + rl;
      int kbp = kq ^ ((r >> 1) & 3);
      af[i] = *reinterpret_cast<const bf16x8*>(&As[cur][r * 32 + kbp * 8]);
    }
#pragma unroll
    for (int j = 0; j < NJ; ++j) {
      int r = wc * (TN / 2) + j * 16 + rl;
      int kbp = kq ^ ((r >> 1) & 3);
      bfr[j] = *reinterpret_cast<const bf16x8*>(&Bs[cur][r * 32 + kbp * 8]);
    }
#pragma unroll
    for (int i = 0; i < MI; ++i)
#pragma unroll
      for (int j = 0; j < NJ; ++j)
        acc[i][j] = __builtin_amdgcn_mfma_f32_16x16x32_bf16(af[i], bfr[j], acc[i][j], 0, 0, 0);
    if (++cur >= 3) cur = 0;
  }

  const int rq = lane >> 4, cl = lane & 15;
  if (SPLIT) {
    float* Pp = P + (size_t)bz * M * 1024;
#pragma unroll
    for (int j = 0; j < NJ; ++j) {
      int gcol = bn * TN + wc * (TN / 2) + j * 16 + cl;
#pragma unroll
      for (int i = 0; i < MI; ++i) {
        int grow = bm * TM + wr * (TM / 2) + i * 16 + rq * 4;
#pragma unroll
        for (int reg = 0; reg < 4; ++reg)
          Pp[(size_t)(grow + reg) * 1024 + gcol] = acc[i][j][reg];
      }
    }
  } else {
#pragma unroll
    for (int j = 0; j < NJ; ++j) {
      int gcol = bn * TN + wc * (TN / 2) + j * 16 + cl;
      float bv = bias[gcol];
#pragma unroll
      for (int i = 0; i < MI; ++i) {
        int grow = bm * TM + wr * (TM / 2) + i * 16 + rq * 4;
#pragma unroll
        for (int reg = 0; reg < 4; ++reg) {
          float v = acc[i][j][reg] + bv;
          v = v > 0.0f ? v : 0.0f;
          C[(size_t)(grow + reg) * 1024 + gcol] = (bf16_t)v;
        }
      }
    }
  }
}

// ---------------- split-K reduce: C = relu(sum_z P[z] + bias), bf16 ----------------
__global__ __launch_bounds__(256) void k_reduce(const float* __restrict__ P,
                                                const float* __restrict__ bias,
                                                bf16_t* __restrict__ C, int M, int ks) {
  constexpr int N = 1024;
  int idx = blockIdx.x * 256 + threadIdx.x;    // over M*N/4
  int col = (idx * 4) & (N - 1);
  int row = (idx * 4) >> 10;
  float4 s = *reinterpret_cast<const float4*>(P + (size_t)row * N + col);
  for (int z = 1; z < ks; ++z) {
    float4 v = *reinterpret_cast<const float4*>(P + ((size_t)z * M + row) * N + col);
    s.x += v.x; s.y += v.y; s.z += v.z; s.w += v.w;
  }
  float4 b = *reinterpret_cast<const float4*>(bias + col);
  bf16x4 o;
  o[0] = (bf16_t)fmaxf(s.x + b.x, 0.0f);
  o[1] = (bf16_t)fmaxf(s.y + b.y, 0.0f);
  o[2] = (bf16_t)fmaxf(s.z + b.z, 0.0f);
  o[3] = (bf16_t)fmaxf(s.w + b.w, 0.0f);
  reinterpret_cast<bf16x4*>(C)[idx] = o;
}

// ---------------- tiny levels (M<=64): wave-per-column GEMV, 8 rows per wave --------
__global__ __launch_bounds__(256) void k_tail(const bf16_t* __restrict__ A,
                                              const bf16_t* __restrict__ Bw,
                                              const float* __restrict__ bias,
                                              bf16_t* __restrict__ C, int M) {
  constexpr int N = 1024, K = 2048;
  const int lane = threadIdx.x & 63;
  const int gw = blockIdx.x * 4 + (threadIdx.x >> 6);
  const int n = gw & (N - 1);
  const int mbase = (gw >> 10) * 8;
  const int k0 = lane * 32;

  float bv[32];
  const bf16_t* bp = Bw + (size_t)n * K + k0;
#pragma unroll
  for (int q = 0; q < 4; ++q) {
    bf16x8 v = *reinterpret_cast<const bf16x8*>(bp + q * 8);
#pragma unroll
    for (int j = 0; j < 8; ++j) bv[q * 8 + j] = (float)v[j];
  }

  float acc[8];
#pragma unroll
  for (int m = 0; m < 8; ++m) {
    const bf16_t* ap = A + (size_t)(mbase + m) * K + k0;
    float s = 0.0f;
#pragma unroll
    for (int q = 0; q < 4; ++q) {
      bf16x8 v = *reinterpret_cast<const bf16x8*>(ap + q * 8);
#pragma unroll
      for (int j = 0; j < 8; ++j) s += (float)v[j] * bv[q * 8 + j];
    }
    acc[m] = s;
  }
#pragma unroll
  for (int m = 0; m < 8; ++m) {
#pragma unroll
    for (int off = 32; off >= 1; off >>= 1) acc[m] += __shfl_xor(acc[m], off, 64);
  }
  if (lane < 8 && mbase + lane < M) {
    float v = acc[lane] + bias[n];
    v = v > 0.0f ? v : 0.0f;
    C[(size_t)(mbase + lane) * N + n] = (bf16_t)v;
  }
}

// ---------------- fused logits + log_softmax: one block per batch row -------------
__global__ __launch_bounds__(1024) void k_head(const bf16_t* __restrict__ root,
                                               const bf16_t* __restrict__ Ow,
                                               const float* __restrict__ Ob,
                                               float* __restrict__ out) {
  const int b = blockIdx.x;            // 8 blocks
  const int o = threadIdx.x;           // 1024 outputs
  const int wave = o >> 6, lane = o & 63;
  __shared__ float red[32];

  const bf16_t* r = root + b * 1024;
  const bf16_t* w = Ow + (size_t)o * 1024;
  float s = 0.0f;
#pragma unroll 4
  for (int k = 0; k < 1024; k += 8) {
    bf16x8 rv = *reinterpret_cast<const bf16x8*>(r + k);
    bf16x8 wv = *reinterpret_cast<const bf16x8*>(w + k);
#pragma unroll
    for (int j = 0; j < 8; ++j) s += (float)rv[j] * (float)wv[j];
  }
  float x = s + Ob[o];

  float m = x;
#pragma unroll
  for (int off = 32; off >= 1; off >>= 1) m = fmaxf(m, __shfl_xor(m, off, 64));
  if (lane == 0) red[wave] = m;
  __syncthreads();
  float mm = red[0];
#pragma unroll
  for (int i = 1; i < 16; ++i) mm = fmaxf(mm, red[i]);
  float e = expf(x - mm);
  float se = e;
#pragma unroll
  for (int off = 32; off >= 1; off >>= 1) se += __shfl_xor(se, off, 64);
  if (lane == 0) red[16 + wave] = se;
  __syncthreads();
  float tot = 0.0f;
#pragma unroll
  for (int i = 0; i < 16; ++i) tot += red[16 + i];
  out[b * 1024 + o] = x - (mm + logf(tot));
}

// ---------------- launch ----------------
extern "C" void kernel_launch(void* const* d_in, const int* in_sizes, int n_in,
                              void* d_out, int out_size, void* d_ws, size_t ws_size,
                              hipStream_t stream) {
  const float* leaves = (const float*)d_in[0];
  const float* V_w = (const float*)d_in[1];
  const float* V_b = (const float*)d_in[2];
  const float* U_w = (const float*)d_in[3];
  const float* U_b = (const float*)d_in[4];
  const float* W_w = (const float*)d_in[5];
  const float* W_b = (const float*)d_in[6];
  const float* O_w = (const float*)d_in[7];
  const float* O_b = (const float*)d_in[8];
  float* out = (float*)d_out;

  char* ws = (char*)d_ws;
  size_t off = 0;
  auto alloc = [&](size_t bytes) -> void* {
    off = (off + 255) & ~(size_t)255;
    void* p = ws + off;
    off += bytes;
    return p;
  };

  const size_t MB16 = (size_t)8192 * 1024 * 2;
  bf16_t* leaves_bf = (bf16_t*)alloc(MB16);
  bf16_t* Vw_bf = (bf16_t*)alloc((size_t)1024 * 1024 * 2);
  bf16_t* UW_bf = (bf16_t*)alloc((size_t)2 * 1024 * 1024 * 2);
  bf16_t* Ow_bf = (bf16_t*)alloc((size_t)1024 * 1024 * 2);
  float* buw = (float*)alloc(1024 * 4);
  bf16_t* hA = (bf16_t*)alloc(MB16);
  float* Pbuf = (float*)alloc((size_t)2 * 4096 * 1024 * 4);   // 32 MB fp32 partials
  (void)ws_size; (void)in_sizes; (void)n_in; (void)out_size;

  // 1: fused converts
  k_cvt_all<<<2048, 256, 0, stream>>>(leaves, V_w, O_w, U_w, W_w, U_b, W_b,
                                      leaves_bf, Vw_bf, Ow_bf, UW_bf, buw);

  // 2: L0 GEMM 8192x1024, K=1024, 128x128 tile -> grid(64,8) = 512 blocks
  k_gemm<128, 128, false><<<dim3(64, 8), 256, 0, stream>>>(
      leaves_bf, Vw_bf, V_b, hA, nullptr, 8192, 1024, 1024);

  bf16_t* src = hA;
  bf16_t* dst = leaves_bf;
  auto swap = [&]() { bf16_t* t = src; src = dst; dst = t; };

  // 3: M=4096, K=2048, 128x128 split-K2 -> grid(32,8,2) = 512 blocks
  k_gemm<128, 128, true><<<dim3(32, 8, 2), 256, 0, stream>>>(
      src, UW_bf, nullptr, nullptr, Pbuf, 4096, 2048, 1024);
  k_reduce<<<4096 * 1024 / 4 / 256, 256, 0, stream>>>(Pbuf, buw, dst, 4096, 2);
  swap();
  // 4: M=2048 split-K2 -> 512 blocks
  k_gemm<64, 128, true><<<dim3(32, 8, 2), 256, 0, stream>>>(
      src, UW_bf, nullptr, nullptr, Pbuf, 2048, 2048, 1024);
  k_reduce<<<2048 * 1024 / 4 / 256, 256, 0, stream>>>(Pbuf, buw, dst, 2048, 2);
  swap();
  // 5: M=1024 split-K4 -> 512 blocks
  k_gemm<64, 128, true><<<dim3(16, 8, 4), 256, 0, stream>>>(
      src, UW_bf, nullptr, nullptr, Pbuf, 1024, 2048, 512);
  k_reduce<<<1024 * 1024 / 4 / 256, 256, 0, stream>>>(Pbuf, buw, dst, 1024, 4);
  swap();
  // 6: M=512 split-K4 -> 256 blocks
  k_gemm<64, 128, true><<<dim3(8, 8, 4), 256, 0, stream>>>(
      src, UW_bf, nullptr, nullptr, Pbuf, 512, 2048, 512);
  k_reduce<<<512 * 1024 / 4 / 256, 256, 0, stream>>>(Pbuf, buw, dst, 512, 4);
  swap();
  // 7: M=256 split-K8 -> 256 blocks
  k_gemm<64, 128, true><<<dim3(4, 8, 8), 256, 0, stream>>>(
      src, UW_bf, nullptr, nullptr, Pbuf, 256, 2048, 256);
  k_reduce<<<256 * 1024 / 4 / 256, 256, 0, stream>>>(Pbuf, buw, dst, 256, 8);
  swap();
  // 8: M=128 split-K8 -> 128 blocks
  k_gemm<64, 128, true><<<dim3(2, 8, 8), 256, 0, stream>>>(
      src, UW_bf, nullptr, nullptr, Pbuf, 128, 2048, 256);
  k_reduce<<<128 * 1024 / 4 / 256, 256, 0, stream>>>(Pbuf, buw, dst, 128, 8);
  swap();
  // 9-12: tails M=64..8 (wave-per-column GEMV)
  for (int M = 64; M >= 8; M >>= 1) {
    int blocks = (M / 8) * 1024 / 4;
    k_tail<<<blocks, 256, 0, stream>>>(src, UW_bf, buw, dst, M);
    swap();
  }

  // 13: fused logits + log_softmax
  k_head<<<8, 1024, 0, stream>>>(src, Ow_bf, O_b, out);
}

// Round 8
// 216.145 us; speedup vs baseline: 9.9535x; 1.2489x over previous
//
#include <hip/hip_runtime.h>
#include <hip/hip_bf16.h>
#include <math.h>

typedef __bf16 bf16_t;
typedef __bf16 bf16x8 __attribute__((ext_vector_type(8)));
typedef __bf16 bf16x4 __attribute__((ext_vector_type(4)));
typedef float  f32x4  __attribute__((ext_vector_type(4)));

#define GLD_LDS16(g, l)                                                          \
  __builtin_amdgcn_global_load_lds((const __attribute__((address_space(1))) void*)(g), \
                                   (__attribute__((address_space(3))) void*)(l), 16, 0, 0)

// ---------------- fused converts: leaves/V_w/O_w -> bf16, UW=[U|W], buw=Ub+Wb -------
__global__ __launch_bounds__(256) void k_cvt_all(const float* __restrict__ leaves,
                                                 const float* __restrict__ V_w,
                                                 const float* __restrict__ O_w,
                                                 const float* __restrict__ U_w,
                                                 const float* __restrict__ W_w,
                                                 const float* __restrict__ U_b,
                                                 const float* __restrict__ W_b,
                                                 bf16_t* __restrict__ leaves_bf,
                                                 bf16_t* __restrict__ Vw_bf,
                                                 bf16_t* __restrict__ Ow_bf,
                                                 bf16_t* __restrict__ UW_bf,
                                                 float* __restrict__ buw) {
  const int gtid = blockIdx.x * 256 + threadIdx.x;
  const int G = gridDim.x * 256;
  for (int i = gtid; i < 2097152; i += G) {            // leaves: 8M elems / 4
    float4 v = reinterpret_cast<const float4*>(leaves)[i];
    bf16x4 o; o[0] = (bf16_t)v.x; o[1] = (bf16_t)v.y; o[2] = (bf16_t)v.z; o[3] = (bf16_t)v.w;
    reinterpret_cast<bf16x4*>(leaves_bf)[i] = o;
  }
  for (int i = gtid; i < 262144; i += G) {             // V_w
    float4 v = reinterpret_cast<const float4*>(V_w)[i];
    bf16x4 o; o[0] = (bf16_t)v.x; o[1] = (bf16_t)v.y; o[2] = (bf16_t)v.z; o[3] = (bf16_t)v.w;
    reinterpret_cast<bf16x4*>(Vw_bf)[i] = o;
  }
  for (int i = gtid; i < 262144; i += G) {             // O_w
    float4 v = reinterpret_cast<const float4*>(O_w)[i];
    bf16x4 o; o[0] = (bf16_t)v.x; o[1] = (bf16_t)v.y; o[2] = (bf16_t)v.z; o[3] = (bf16_t)v.w;
    reinterpret_cast<bf16x4*>(Ow_bf)[i] = o;
  }
  for (int idx = gtid; idx < 524288; idx += G) {       // UW = [U|W] concat along K
    int i = idx * 4;
    int g = i >> 11;
    int k = i & 2047;
    const float* src = (k < 1024) ? (U_w + g * 1024 + k) : (W_w + g * 1024 + (k - 1024));
    float4 v = *reinterpret_cast<const float4*>(src);
    bf16x4 o; o[0] = (bf16_t)v.x; o[1] = (bf16_t)v.y; o[2] = (bf16_t)v.z; o[3] = (bf16_t)v.w;
    reinterpret_cast<bf16x4*>(UW_bf)[idx] = o;
  }
  if (gtid < 1024) buw[gtid] = U_b[gtid] + W_b[gtid];
}

// ---------------- GEMM: TMxTN tile, BK=32, 3-buf 2-deep pipeline, counted vmcnt -----
// C[M,1024] = relu(A[M,Kstride(chunk)] @ Bw[1024,Kstride]^T + bias), or fp32 partials.
template <int TM, int TN, bool SPLIT>
__global__ __launch_bounds__(256, (TM == 128 ? 3 : 4)) void k_gemm(
    const bf16_t* __restrict__ A, const bf16_t* __restrict__ Bw,
    const float* __restrict__ bias, bf16_t* __restrict__ C,
    float* __restrict__ P, int M, int Kstride, int kchunk) {
  constexpr int MI = TM / 32;                 // row frags per wave
  constexpr int NJ = TN / 32;                 // col frags per wave
  constexpr int VM = TM / 64 + TN / 64;       // per-thread loads per stage
  __shared__ bf16_t As[3][TM * 32];
  __shared__ bf16_t Bs[3][TN * 32];

  const int tid = threadIdx.x;
  const int lane = tid & 63;
  const int wave = tid >> 6;
  const int wr = wave >> 1, wc = wave & 1;
  const int bm = blockIdx.x, bn = blockIdx.y, bz = blockIdx.z;

  const bf16_t* Abase = A + (size_t)bm * TM * Kstride + (size_t)bz * kchunk;
  const bf16_t* Bbase = Bw + (size_t)bn * TN * Kstride + (size_t)bz * kchunk;

  f32x4 acc[MI][NJ] = {};
  const int rl = lane & 15, kq = lane >> 4;

  auto stage = [&](int buf, int ko) {
#pragma unroll
    for (int it = 0; it < TM / 64; ++it) {    // A: TM rows x 4 chunks of 8 bf16
      int c = tid + 256 * it;
      int r = c >> 2, kbp = c & 3;
      int kb = kbp ^ ((r >> 1) & 3);          // inverse swizzle on global source
      GLD_LDS16(Abase + (size_t)r * Kstride + ko + kb * 8, &As[buf][c * 8]);
    }
#pragma unroll
    for (int it = 0; it < TN / 64; ++it) {    // B: TN rows x 4 chunks
      int c = tid + 256 * it;
      int r = c >> 2, kbp = c & 3;
      int kb = kbp ^ ((r >> 1) & 3);
      GLD_LDS16(Bbase + (size_t)r * Kstride + ko + kb * 8, &Bs[buf][c * 8]);
    }
  };

  const int kiters = kchunk >> 5;
  stage(0, 0);
  stage(1, 32);

  int cur = 0;
  for (int t = 0; t < kiters; ++t) {
    if (t + 1 < kiters) asm volatile("s_waitcnt vmcnt(%0)" :: "i"(VM) : "memory");
    else                asm volatile("s_waitcnt vmcnt(0)" ::: "memory");
    __builtin_amdgcn_s_barrier();
    __builtin_amdgcn_sched_barrier(0);
    if (t + 2 < kiters) {
      int b2 = cur + 2; if (b2 >= 3) b2 -= 3;
      stage(b2, (t + 2) * 32);
    }
    bf16x8 af[MI], bfr[NJ];
#pragma unroll
    for (int i = 0; i < MI; ++i) {
      int r = wr * (TM / 2) + i * 16 + rl;
      int kbp = kq ^ ((r >> 1) & 3);
      af[i] = *reinterpret_cast<const bf16x8*>(&As[cur][r * 32 + kbp * 8]);
    }
#pragma unroll
    for (int j = 0; j < NJ; ++j) {
      int r = wc * (TN / 2) + j * 16 + rl;
      int kbp = kq ^ ((r >> 1) & 3);
      bfr[j] = *reinterpret_cast<const bf16x8*>(&Bs[cur][r * 32 + kbp * 8]);
    }
#pragma unroll
    for (int i = 0; i < MI; ++i)
#pragma unroll
      for (int j = 0; j < NJ; ++j)
        acc[i][j] = __builtin_amdgcn_mfma_f32_16x16x32_bf16(af[i], bfr[j], acc[i][j], 0, 0, 0);
    if (++cur >= 3) cur = 0;
  }

  const int rq = lane >> 4, cl = lane & 15;
  if (SPLIT) {
    float* Pp = P + (size_t)bz * M * 1024;
#pragma unroll
    for (int j = 0; j < NJ; ++j) {
      int gcol = bn * TN + wc * (TN / 2) + j * 16 + cl;
#pragma unroll
      for (int i = 0; i < MI; ++i) {
        int grow = bm * TM + wr * (TM / 2) + i * 16 + rq * 4;
#pragma unroll
        for (int reg = 0; reg < 4; ++reg)
          Pp[(size_t)(grow + reg) * 1024 + gcol] = acc[i][j][reg];
      }
    }
  } else {
#pragma unroll
    for (int j = 0; j < NJ; ++j) {
      int gcol = bn * TN + wc * (TN / 2) + j * 16 + cl;
      float bv = bias[gcol];
#pragma unroll
      for (int i = 0; i < MI; ++i) {
        int grow = bm * TM + wr * (TM / 2) + i * 16 + rq * 4;
#pragma unroll
        for (int reg = 0; reg < 4; ++reg) {
          float v = acc[i][j][reg] + bv;
          v = v > 0.0f ? v : 0.0f;
          C[(size_t)(grow + reg) * 1024 + gcol] = (bf16_t)v;
        }
      }
    }
  }
}

// ---------------- split-K reduce: C = relu(sum_z P[z] + bias), bf16 ----------------
__global__ __launch_bounds__(256) void k_reduce(const float* __restrict__ P,
                                                const float* __restrict__ bias,
                                                bf16_t* __restrict__ C, int M, int ks) {
  constexpr int N = 1024;
  int idx = blockIdx.x * 256 + threadIdx.x;    // over M*N/4
  int col = (idx * 4) & (N - 1);
  int row = (idx * 4) >> 10;
  float4 s = *reinterpret_cast<const float4*>(P + (size_t)row * N + col);
  for (int z = 1; z < ks; ++z) {
    float4 v = *reinterpret_cast<const float4*>(P + ((size_t)z * M + row) * N + col);
    s.x += v.x; s.y += v.y; s.z += v.z; s.w += v.w;
  }
  float4 b = *reinterpret_cast<const float4*>(bias + col);
  bf16x4 o;
  o[0] = (bf16_t)fmaxf(s.x + b.x, 0.0f);
  o[1] = (bf16_t)fmaxf(s.y + b.y, 0.0f);
  o[2] = (bf16_t)fmaxf(s.z + b.z, 0.0f);
  o[3] = (bf16_t)fmaxf(s.w + b.w, 0.0f);
  reinterpret_cast<bf16x4*>(C)[idx] = o;
}

// ---------------- small-M GEMV: wave computes 8 rows x 1 col --------
// KK = reduction length; out fp32 or bf16; optional relu.
template <int KK, bool RELU, bool F32OUT>
__global__ __launch_bounds__(256) void k_tail(const bf16_t* __restrict__ A,
                                              const bf16_t* __restrict__ Bw,
                                              const float* __restrict__ bias,
                                              void* __restrict__ Cout, int M) {
  constexpr int N = 1024;
  constexpr int KPL = KK / 64;                 // bf16 per lane
  const int lane = threadIdx.x & 63;
  const int gw = blockIdx.x * 4 + (threadIdx.x >> 6);
  const int n = gw & (N - 1);
  const int mbase = (gw >> 10) * 8;
  const int k0 = lane * KPL;

  float bv[KPL];
  const bf16_t* bp = Bw + (size_t)n * KK + k0;
#pragma unroll
  for (int q = 0; q < KPL / 8; ++q) {
    bf16x8 v = *reinterpret_cast<const bf16x8*>(bp + q * 8);
#pragma unroll
    for (int j = 0; j < 8; ++j) bv[q * 8 + j] = (float)v[j];
  }

  float acc[8];
#pragma unroll
  for (int m = 0; m < 8; ++m) {
    const bf16_t* ap = A + (size_t)(mbase + m) * KK + k0;
    float s = 0.0f;
#pragma unroll
    for (int q = 0; q < KPL / 8; ++q) {
      bf16x8 v = *reinterpret_cast<const bf16x8*>(ap + q * 8);
#pragma unroll
      for (int j = 0; j < 8; ++j) s += (float)v[j] * bv[q * 8 + j];
    }
    acc[m] = s;
  }
#pragma unroll
  for (int m = 0; m < 8; ++m) {
#pragma unroll
    for (int off = 32; off >= 1; off >>= 1) acc[m] += __shfl_xor(acc[m], off, 64);
  }
  if (lane < 8 && mbase + lane < M) {
    float v = acc[lane] + bias[n];
    if (RELU) v = v > 0.0f ? v : 0.0f;
    if (F32OUT) ((float*)Cout)[(size_t)(mbase + lane) * N + n] = v;
    else        ((bf16_t*)Cout)[(size_t)(mbase + lane) * N + n] = (bf16_t)v;
  }
}

// ---------------- log_softmax over 8 rows x 1024 (tiny) ----------------
__global__ __launch_bounds__(256) void k_logsoftmax(const float* __restrict__ logits,
                                                    float* __restrict__ out) {
  int b = blockIdx.x;
  const float* x = logits + b * 1024;
  int tid = threadIdx.x;
  int wave = tid >> 6, lane = tid & 63;
  __shared__ float red[8];

  float m = -1e30f;
  for (int i = tid; i < 1024; i += 256) m = fmaxf(m, x[i]);
#pragma unroll
  for (int off = 32; off >= 1; off >>= 1) m = fmaxf(m, __shfl_xor(m, off, 64));
  if (lane == 0) red[wave] = m;
  __syncthreads();
  m = fmaxf(fmaxf(red[0], red[1]), fmaxf(red[2], red[3]));
  float s = 0.0f;
  for (int i = tid; i < 1024; i += 256) s += expf(x[i] - m);
#pragma unroll
  for (int off = 32; off >= 1; off >>= 1) s += __shfl_xor(s, off, 64);
  if (lane == 0) red[wave] = s;
  __syncthreads();
  float lse = m + logf(red[0] + red[1] + red[2] + red[3]);
  for (int i = tid; i < 1024; i += 256) out[b * 1024 + i] = x[i] - lse;
}

// ---------------- launch ----------------
extern "C" void kernel_launch(void* const* d_in, const int* in_sizes, int n_in,
                              void* d_out, int out_size, void* d_ws, size_t ws_size,
                              hipStream_t stream) {
  const float* leaves = (const float*)d_in[0];
  const float* V_w = (const float*)d_in[1];
  const float* V_b = (const float*)d_in[2];
  const float* U_w = (const float*)d_in[3];
  const float* U_b = (const float*)d_in[4];
  const float* W_w = (const float*)d_in[5];
  const float* W_b = (const float*)d_in[6];
  const float* O_w = (const float*)d_in[7];
  const float* O_b = (const float*)d_in[8];
  float* out = (float*)d_out;

  char* ws = (char*)d_ws;
  size_t off = 0;
  auto alloc = [&](size_t bytes) -> void* {
    off = (off + 255) & ~(size_t)255;
    void* p = ws + off;
    off += bytes;
    return p;
  };

  const size_t MB16 = (size_t)8192 * 1024 * 2;
  bf16_t* leaves_bf = (bf16_t*)alloc(MB16);
  bf16_t* Vw_bf = (bf16_t*)alloc((size_t)1024 * 1024 * 2);
  bf16_t* UW_bf = (bf16_t*)alloc((size_t)2 * 1024 * 1024 * 2);
  bf16_t* Ow_bf = (bf16_t*)alloc((size_t)1024 * 1024 * 2);
  float* buw = (float*)alloc(1024 * 4);
  bf16_t* hA = (bf16_t*)alloc(MB16);
  float* logits = (float*)alloc(8 * 1024 * 4);
  float* Pbuf = (float*)alloc((size_t)2 * 4096 * 1024 * 4);   // 32 MB fp32 partials
  (void)ws_size; (void)in_sizes; (void)n_in; (void)out_size;

  // 1: fused converts
  k_cvt_all<<<2048, 256, 0, stream>>>(leaves, V_w, O_w, U_w, W_w, U_b, W_b,
                                      leaves_bf, Vw_bf, Ow_bf, UW_bf, buw);

  // 2: L0 GEMM 8192x1024, K=1024, 128x128 tile -> grid(64,8) = 512 blocks
  k_gemm<128, 128, false><<<dim3(64, 8), 256, 0, stream>>>(
      leaves_bf, Vw_bf, V_b, hA, nullptr, 8192, 1024, 1024);

  bf16_t* src = hA;
  bf16_t* dst = leaves_bf;
  auto swap = [&]() { bf16_t* t = src; src = dst; dst = t; };

  // 3: M=4096, K=2048, 128x128 split-K2 -> grid(32,8,2) = 512 blocks
  k_gemm<128, 128, true><<<dim3(32, 8, 2), 256, 0, stream>>>(
      src, UW_bf, nullptr, nullptr, Pbuf, 4096, 2048, 1024);
  k_reduce<<<4096 * 1024 / 4 / 256, 256, 0, stream>>>(Pbuf, buw, dst, 4096, 2);
  swap();
  // 4: M=2048 split-K2 -> 512 blocks
  k_gemm<64, 128, true><<<dim3(32, 8, 2), 256, 0, stream>>>(
      src, UW_bf, nullptr, nullptr, Pbuf, 2048, 2048, 1024);
  k_reduce<<<2048 * 1024 / 4 / 256, 256, 0, stream>>>(Pbuf, buw, dst, 2048, 2);
  swap();
  // 5: M=1024 split-K4 -> 512 blocks
  k_gemm<64, 128, true><<<dim3(16, 8, 4), 256, 0, stream>>>(
      src, UW_bf, nullptr, nullptr, Pbuf, 1024, 2048, 512);
  k_reduce<<<1024 * 1024 / 4 / 256, 256, 0, stream>>>(Pbuf, buw, dst, 1024, 4);
  swap();
  // 6: M=512 split-K4 -> 256 blocks
  k_gemm<64, 128, true><<<dim3(8, 8, 4), 256, 0, stream>>>(
      src, UW_bf, nullptr, nullptr, Pbuf, 512, 2048, 512);
  k_reduce<<<512 * 1024 / 4 / 256, 256, 0, stream>>>(Pbuf, buw, dst, 512, 4);
  swap();
  // 7: M=256 split-K8 -> 256 blocks
  k_gemm<64, 128, true><<<dim3(4, 8, 8), 256, 0, stream>>>(
      src, UW_bf, nullptr, nullptr, Pbuf, 256, 2048, 256);
  k_reduce<<<256 * 1024 / 4 / 256, 256, 0, stream>>>(Pbuf, buw, dst, 256, 8);
  swap();
  // 8: M=128 split-K8 -> 128 blocks
  k_gemm<64, 128, true><<<dim3(2, 8, 8), 256, 0, stream>>>(
      src, UW_bf, nullptr, nullptr, Pbuf, 128, 2048, 256);
  k_reduce<<<128 * 1024 / 4 / 256, 256, 0, stream>>>(Pbuf, buw, dst, 128, 8);
  swap();
  // 9-12: tails M=64..8 (wave-per-column GEMV, K=2048)
  for (int M = 64; M >= 8; M >>= 1) {
    int blocks = (M / 8) * 1024 / 4;
    k_tail<2048, true, false><<<blocks, 256, 0, stream>>>(src, UW_bf, buw, dst, M);
    swap();
  }

  // 13: logits as wide GEMV (M=8, K=1024, fp32 out, no relu) -> 256 blocks
  k_tail<1024, false, true><<<256, 256, 0, stream>>>(src, Ow_bf, O_b, logits, 8);
  // 14: log_softmax (tiny)
  k_logsoftmax<<<8, 256, 0, stream>>>(logits, out);
}

// Round 9
// 206.963 us; speedup vs baseline: 10.3951x; 1.0444x over previous
//
#include <hip/hip_runtime.h>
#include <hip/hip_bf16.h>
#include <math.h>

typedef __bf16 bf16_t;
typedef __bf16 bf16x8 __attribute__((ext_vector_type(8)));
typedef __bf16 bf16x4 __attribute__((ext_vector_type(4)));
typedef float  f32x4  __attribute__((ext_vector_type(4)));

#define GLD_LDS16(g, l)                                                          \
  __builtin_amdgcn_global_load_lds((const __attribute__((address_space(1))) void*)(g), \
                                   (__attribute__((address_space(3))) void*)(l), 16, 0, 0)

// ---------------- fused converts: leaves/V_w/O_w -> bf16, UW=[U|W], buw=Ub+Wb -------
__global__ __launch_bounds__(256) void k_cvt_all(const float* __restrict__ leaves,
                                                 const float* __restrict__ V_w,
                                                 const float* __restrict__ O_w,
                                                 const float* __restrict__ U_w,
                                                 const float* __restrict__ W_w,
                                                 const float* __restrict__ U_b,
                                                 const float* __restrict__ W_b,
                                                 bf16_t* __restrict__ leaves_bf,
                                                 bf16_t* __restrict__ Vw_bf,
                                                 bf16_t* __restrict__ Ow_bf,
                                                 bf16_t* __restrict__ UW_bf,
                                                 float* __restrict__ buw) {
  const int gtid = blockIdx.x * 256 + threadIdx.x;
  const int G = gridDim.x * 256;
  for (int i = gtid; i < 2097152; i += G) {            // leaves: 8M elems / 4
    float4 v = reinterpret_cast<const float4*>(leaves)[i];
    bf16x4 o; o[0] = (bf16_t)v.x; o[1] = (bf16_t)v.y; o[2] = (bf16_t)v.z; o[3] = (bf16_t)v.w;
    reinterpret_cast<bf16x4*>(leaves_bf)[i] = o;
  }
  for (int i = gtid; i < 262144; i += G) {             // V_w
    float4 v = reinterpret_cast<const float4*>(V_w)[i];
    bf16x4 o; o[0] = (bf16_t)v.x; o[1] = (bf16_t)v.y; o[2] = (bf16_t)v.z; o[3] = (bf16_t)v.w;
    reinterpret_cast<bf16x4*>(Vw_bf)[i] = o;
  }
  for (int i = gtid; i < 262144; i += G) {             // O_w
    float4 v = reinterpret_cast<const float4*>(O_w)[i];
    bf16x4 o; o[0] = (bf16_t)v.x; o[1] = (bf16_t)v.y; o[2] = (bf16_t)v.z; o[3] = (bf16_t)v.w;
    reinterpret_cast<bf16x4*>(Ow_bf)[i] = o;
  }
  for (int idx = gtid; idx < 524288; idx += G) {       // UW = [U|W] concat along K
    int i = idx * 4;
    int g = i >> 11;
    int k = i & 2047;
    const float* src = (k < 1024) ? (U_w + g * 1024 + k) : (W_w + g * 1024 + (k - 1024));
    float4 v = *reinterpret_cast<const float4*>(src);
    bf16x4 o; o[0] = (bf16_t)v.x; o[1] = (bf16_t)v.y; o[2] = (bf16_t)v.z; o[3] = (bf16_t)v.w;
    reinterpret_cast<bf16x4*>(UW_bf)[idx] = o;
  }
  if (gtid < 1024) buw[gtid] = U_b[gtid] + W_b[gtid];
}

// ---------------- GEMM: TMxTN tile, BK=32, 4-buf DEPTH-3 pipeline, counted vmcnt ----
// C[M,1024] = relu(A[M,Kstride(chunk)] @ Bw[1024,Kstride]^T + bias), or bf16 partials.
// Steady state: wait vmcnt(2*VM) -> tile t landed, t+1,t+2 in flight (issued 2-3
// iters = ~600+ cyc earlier, covering L2/HBM latency). Stage t+3 after barrier.
template <int TM, int TN, bool SPLIT>
__global__ __launch_bounds__(256, (TM == 128 ? 2 : 3)) void k_gemm(
    const bf16_t* __restrict__ A, const bf16_t* __restrict__ Bw,
    const float* __restrict__ bias, bf16_t* __restrict__ C,
    bf16_t* __restrict__ P, int M, int Kstride, int kchunk) {
  constexpr int MI = TM / 32;                 // row frags per wave
  constexpr int NJ = TN / 32;                 // col frags per wave
  constexpr int VM = TM / 64 + TN / 64;       // per-thread loads per stage
  __shared__ bf16_t As[4][TM * 32];
  __shared__ bf16_t Bs[4][TN * 32];

  const int tid = threadIdx.x;
  const int lane = tid & 63;
  const int wave = tid >> 6;
  const int wr = wave >> 1, wc = wave & 1;
  const int bm = blockIdx.x, bn = blockIdx.y, bz = blockIdx.z;

  const bf16_t* Abase = A + (size_t)bm * TM * Kstride + (size_t)bz * kchunk;
  const bf16_t* Bbase = Bw + (size_t)bn * TN * Kstride + (size_t)bz * kchunk;

  f32x4 acc[MI][NJ] = {};
  const int rl = lane & 15, kq = lane >> 4;

  auto stage = [&](int buf, int ko) {
#pragma unroll
    for (int it = 0; it < TM / 64; ++it) {    // A: TM rows x 4 chunks of 8 bf16
      int c = tid + 256 * it;
      int r = c >> 2, kbp = c & 3;
      int kb = kbp ^ ((r >> 1) & 3);          // inverse swizzle on global source
      GLD_LDS16(Abase + (size_t)r * Kstride + ko + kb * 8, &As[buf][c * 8]);
    }
#pragma unroll
    for (int it = 0; it < TN / 64; ++it) {    // B: TN rows x 4 chunks
      int c = tid + 256 * it;
      int r = c >> 2, kbp = c & 3;
      int kb = kbp ^ ((r >> 1) & 3);
      GLD_LDS16(Bbase + (size_t)r * Kstride + ko + kb * 8, &Bs[buf][c * 8]);
    }
  };

  const int kiters = kchunk >> 5;
  stage(0, 0);
  if (kiters > 1) stage(1, 32);
  if (kiters > 2) stage(2, 64);

  int cur = 0;
  for (int t = 0; t < kiters; ++t) {
    const int nin = kiters - 1 - t;           // tiles still in flight beyond t
    if (nin >= 2)      asm volatile("s_waitcnt vmcnt(%0)" :: "i"(2 * VM) : "memory");
    else if (nin == 1) asm volatile("s_waitcnt vmcnt(%0)" :: "i"(VM) : "memory");
    else               asm volatile("s_waitcnt vmcnt(0)" ::: "memory");
    __builtin_amdgcn_s_barrier();
    __builtin_amdgcn_sched_barrier(0);
    if (t + 3 < kiters) {
      int b3 = cur + 3; if (b3 >= 4) b3 -= 4;  // buf of tile t-1, freed at this barrier
      stage(b3, (t + 3) * 32);
    }
    bf16x8 af[MI], bfr[NJ];
#pragma unroll
    for (int i = 0; i < MI; ++i) {
      int r = wr * (TM / 2) + i * 16 + rl;
      int kbp = kq ^ ((r >> 1) & 3);
      af[i] = *reinterpret_cast<const bf16x8*>(&As[cur][r * 32 + kbp * 8]);
    }
#pragma unroll
    for (int j = 0; j < NJ; ++j) {
      int r = wc * (TN / 2) + j * 16 + rl;
      int kbp = kq ^ ((r >> 1) & 3);
      bfr[j] = *reinterpret_cast<const bf16x8*>(&Bs[cur][r * 32 + kbp * 8]);
    }
#pragma unroll
    for (int i = 0; i < MI; ++i)
#pragma unroll
      for (int j = 0; j < NJ; ++j)
        acc[i][j] = __builtin_amdgcn_mfma_f32_16x16x32_bf16(af[i], bfr[j], acc[i][j], 0, 0, 0);
    if (++cur >= 4) cur = 0;
  }

  const int rq = lane >> 4, cl = lane & 15;
  if (SPLIT) {
    bf16_t* Pp = P + (size_t)bz * M * 1024;
#pragma unroll
    for (int j = 0; j < NJ; ++j) {
      int gcol = bn * TN + wc * (TN / 2) + j * 16 + cl;
#pragma unroll
      for (int i = 0; i < MI; ++i) {
        int grow = bm * TM + wr * (TM / 2) + i * 16 + rq * 4;
#pragma unroll
        for (int reg = 0; reg < 4; ++reg)
          Pp[(size_t)(grow + reg) * 1024 + gcol] = (bf16_t)acc[i][j][reg];
      }
    }
  } else {
#pragma unroll
    for (int j = 0; j < NJ; ++j) {
      int gcol = bn * TN + wc * (TN / 2) + j * 16 + cl;
      float bv = bias[gcol];
#pragma unroll
      for (int i = 0; i < MI; ++i) {
        int grow = bm * TM + wr * (TM / 2) + i * 16 + rq * 4;
#pragma unroll
        for (int reg = 0; reg < 4; ++reg) {
          float v = acc[i][j][reg] + bv;
          v = v > 0.0f ? v : 0.0f;
          C[(size_t)(grow + reg) * 1024 + gcol] = (bf16_t)v;
        }
      }
    }
  }
}

// ---------------- split-K reduce: C = relu(sum_z P[z] + bias), bf16 partials --------
__global__ __launch_bounds__(256) void k_reduce(const bf16_t* __restrict__ P,
                                                const float* __restrict__ bias,
                                                bf16_t* __restrict__ C, int M, int ks) {
  constexpr int N = 1024;
  int idx = blockIdx.x * 256 + threadIdx.x;    // over M*N/4
  int col = (idx * 4) & (N - 1);
  int row = (idx * 4) >> 10;
  float s0 = 0.0f, s1 = 0.0f, s2 = 0.0f, s3 = 0.0f;
  for (int z = 0; z < ks; ++z) {
    bf16x4 v = *reinterpret_cast<const bf16x4*>(P + ((size_t)z * M + row) * N + col);
    s0 += (float)v[0]; s1 += (float)v[1]; s2 += (float)v[2]; s3 += (float)v[3];
  }
  float4 b = *reinterpret_cast<const float4*>(bias + col);
  bf16x4 o;
  o[0] = (bf16_t)fmaxf(s0 + b.x, 0.0f);
  o[1] = (bf16_t)fmaxf(s1 + b.y, 0.0f);
  o[2] = (bf16_t)fmaxf(s2 + b.z, 0.0f);
  o[3] = (bf16_t)fmaxf(s3 + b.w, 0.0f);
  reinterpret_cast<bf16x4*>(C)[idx] = o;
}

// ---------------- small-M GEMV: wave computes 8 rows x 1 col --------
template <int KK, bool RELU, bool F32OUT>
__global__ __launch_bounds__(256) void k_tail(const bf16_t* __restrict__ A,
                                              const bf16_t* __restrict__ Bw,
                                              const float* __restrict__ bias,
                                              void* __restrict__ Cout, int M) {
  constexpr int N = 1024;
  constexpr int KPL = KK / 64;                 // bf16 per lane
  const int lane = threadIdx.x & 63;
  const int gw = blockIdx.x * 4 + (threadIdx.x >> 6);
  const int n = gw & (N - 1);
  const int mbase = (gw >> 10) * 8;
  const int k0 = lane * KPL;

  float bv[KPL];
  const bf16_t* bp = Bw + (size_t)n * KK + k0;
#pragma unroll
  for (int q = 0; q < KPL / 8; ++q) {
    bf16x8 v = *reinterpret_cast<const bf16x8*>(bp + q * 8);
#pragma unroll
    for (int j = 0; j < 8; ++j) bv[q * 8 + j] = (float)v[j];
  }

  float acc[8];
#pragma unroll
  for (int m = 0; m < 8; ++m) {
    const bf16_t* ap = A + (size_t)(mbase + m) * KK + k0;
    float s = 0.0f;
#pragma unroll
    for (int q = 0; q < KPL / 8; ++q) {
      bf16x8 v = *reinterpret_cast<const bf16x8*>(ap + q * 8);
#pragma unroll
      for (int j = 0; j < 8; ++j) s += (float)v[j] * bv[q * 8 + j];
    }
    acc[m] = s;
  }
#pragma unroll
  for (int m = 0; m < 8; ++m) {
#pragma unroll
    for (int off = 32; off >= 1; off >>= 1) acc[m] += __shfl_xor(acc[m], off, 64);
  }
  if (lane < 8 && mbase + lane < M) {
    float v = acc[lane] + bias[n];
    if (RELU) v = v > 0.0f ? v : 0.0f;
    if (F32OUT) ((float*)Cout)[(size_t)(mbase + lane) * N + n] = v;
    else        ((bf16_t*)Cout)[(size_t)(mbase + lane) * N + n] = (bf16_t)v;
  }
}

// ---------------- log_softmax over 8 rows x 1024 (tiny) ----------------
__global__ __launch_bounds__(256) void k_logsoftmax(const float* __restrict__ logits,
                                                    float* __restrict__ out) {
  int b = blockIdx.x;
  const float* x = logits + b * 1024;
  int tid = threadIdx.x;
  int wave = tid >> 6, lane = tid & 63;
  __shared__ float red[8];

  float m = -1e30f;
  for (int i = tid; i < 1024; i += 256) m = fmaxf(m, x[i]);
#pragma unroll
  for (int off = 32; off >= 1; off >>= 1) m = fmaxf(m, __shfl_xor(m, off, 64));
  if (lane == 0) red[wave] = m;
  __syncthreads();
  m = fmaxf(fmaxf(red[0], red[1]), fmaxf(red[2], red[3]));
  float s = 0.0f;
  for (int i = tid; i < 1024; i += 256) s += expf(x[i] - m);
#pragma unroll
  for (int off = 32; off >= 1; off >>= 1) s += __shfl_xor(s, off, 64);
  if (lane == 0) red[wave] = s;
  __syncthreads();
  float lse = m + logf(red[0] + red[1] + red[2] + red[3]);
  for (int i = tid; i < 1024; i += 256) out[b * 1024 + i] = x[i] - lse;
}

// ---------------- launch ----------------
extern "C" void kernel_launch(void* const* d_in, const int* in_sizes, int n_in,
                              void* d_out, int out_size, void* d_ws, size_t ws_size,
                              hipStream_t stream) {
  const float* leaves = (const float*)d_in[0];
  const float* V_w = (const float*)d_in[1];
  const float* V_b = (const float*)d_in[2];
  const float* U_w = (const float*)d_in[3];
  const float* U_b = (const float*)d_in[4];
  const float* W_w = (const float*)d_in[5];
  const float* W_b = (const float*)d_in[6];
  const float* O_w = (const float*)d_in[7];
  const float* O_b = (const float*)d_in[8];
  float* out = (float*)d_out;

  char* ws = (char*)d_ws;
  size_t off = 0;
  auto alloc = [&](size_t bytes) -> void* {
    off = (off + 255) & ~(size_t)255;
    void* p = ws + off;
    off += bytes;
    return p;
  };

  const size_t MB16 = (size_t)8192 * 1024 * 2;
  bf16_t* leaves_bf = (bf16_t*)alloc(MB16);
  bf16_t* Vw_bf = (bf16_t*)alloc((size_t)1024 * 1024 * 2);
  bf16_t* UW_bf = (bf16_t*)alloc((size_t)2 * 1024 * 1024 * 2);
  bf16_t* Ow_bf = (bf16_t*)alloc((size_t)1024 * 1024 * 2);
  float* buw = (float*)alloc(1024 * 4);
  bf16_t* hA = (bf16_t*)alloc(MB16);
  float* logits = (float*)alloc(8 * 1024 * 4);
  bf16_t* Pbuf = (bf16_t*)alloc((size_t)8 * 4096 * 1024 * 2);   // bf16 partials
  (void)ws_size; (void)in_sizes; (void)n_in; (void)out_size;

  // 1: fused converts
  k_cvt_all<<<2048, 256, 0, stream>>>(leaves, V_w, O_w, U_w, W_w, U_b, W_b,
                                      leaves_bf, Vw_bf, Ow_bf, UW_bf, buw);

  // 2: L0 GEMM 8192x1024, K=1024, 128x128 tile -> grid(64,8) = 512 blocks
  k_gemm<128, 128, false><<<dim3(64, 8), 256, 0, stream>>>(
      leaves_bf, Vw_bf, V_b, hA, nullptr, 8192, 1024, 1024);

  bf16_t* src = hA;
  bf16_t* dst = leaves_bf;
  auto swap = [&]() { bf16_t* t = src; src = dst; dst = t; };

  // 3: M=4096, K=2048, 128x128 split-K2 -> grid(32,8,2) = 512 blocks
  k_gemm<128, 128, true><<<dim3(32, 8, 2), 256, 0, stream>>>(
      src, UW_bf, nullptr, nullptr, Pbuf, 4096, 2048, 1024);
  k_reduce<<<4096 * 1024 / 4 / 256, 256, 0, stream>>>(Pbuf, buw, dst, 4096, 2);
  swap();
  // 4: M=2048 split-K2 -> 512 blocks
  k_gemm<64, 128, true><<<dim3(32, 8, 2), 256, 0, stream>>>(
      src, UW_bf, nullptr, nullptr, Pbuf, 2048, 2048, 1024);
  k_reduce<<<2048 * 1024 / 4 / 256, 256, 0, stream>>>(Pbuf, buw, dst, 2048, 2);
  swap();
  // 5: M=1024 split-K4 -> 512 blocks
  k_gemm<64, 128, true><<<dim3(16, 8, 4), 256, 0, stream>>>(
      src, UW_bf, nullptr, nullptr, Pbuf, 1024, 2048, 512);
  k_reduce<<<1024 * 1024 / 4 / 256, 256, 0, stream>>>(Pbuf, buw, dst, 1024, 4);
  swap();
  // 6: M=512 split-K4 -> 256 blocks
  k_gemm<64, 128, true><<<dim3(8, 8, 4), 256, 0, stream>>>(
      src, UW_bf, nullptr, nullptr, Pbuf, 512, 2048, 512);
  k_reduce<<<512 * 1024 / 4 / 256, 256, 0, stream>>>(Pbuf, buw, dst, 512, 4);
  swap();
  // 7: M=256 split-K8 -> 256 blocks
  k_gemm<64, 128, true><<<dim3(4, 8, 8), 256, 0, stream>>>(
      src, UW_bf, nullptr, nullptr, Pbuf, 256, 2048, 256);
  k_reduce<<<256 * 1024 / 4 / 256, 256, 0, stream>>>(Pbuf, buw, dst, 256, 8);
  swap();
  // 8: M=128 split-K8 -> 128 blocks
  k_gemm<64, 128, true><<<dim3(2, 8, 8), 256, 0, stream>>>(
      src, UW_bf, nullptr, nullptr, Pbuf, 128, 2048, 256);
  k_reduce<<<128 * 1024 / 4 / 256, 256, 0, stream>>>(Pbuf, buw, dst, 128, 8);
  swap();
  // 9-12: tails M=64..8 (wave-per-column GEMV, K=2048)
  for (int M = 64; M >= 8; M >>= 1) {
    int blocks = (M / 8) * 1024 / 4;
    k_tail<2048, true, false><<<blocks, 256, 0, stream>>>(src, UW_bf, buw, dst, M);
    swap();
  }

  // 13: logits as wide GEMV (M=8, K=1024, fp32 out, no relu) -> 256 blocks
  k_tail<1024, false, true><<<256, 256, 0, stream>>>(src, Ow_bf, O_b, logits, 8);
  // 14: log_softmax (tiny)
  k_logsoftmax<<<8, 256, 0, stream>>>(logits, out);
}